// Round 1
// baseline (583.004 us; speedup 1.0000x reference)
//
#include <hip/hip_runtime.h>
#include <hip/hip_fp16.h>

// KbInterpForw: table-based KB NUFFT interpolation, forward.
// x: (2,16,2,512,512) f32, om: (2,2,262144) f32, tables: (2,6145) f32 each.
// out: (2,16,2,262144) f32.
//
// R7 (on top of R6):
//  - interp_sorted: 1 thread per point owning all 16 coils (was 4 lanes x
//    4 coils). Table lookups, coefficient products, f32->f16 cvt/pack and
//    the sin/cos phase were computed 4x redundantly; VALU instrs/point drop
//    ~1.7x. Gather traffic per record unchanged (4x dwordx4 = same 64B line).
//  - sort collapsed 4 passes -> 2: histogram fused into transpose_fp16
//    (global atomics into 2048 counters, hidden under the BW-bound copy);
//    scatter takes pos = atomicAdd(&cursor[g],1) directly. Within-bin order
//    is nondeterministic but inv[] records the exact permutation, so output
//    is unchanged. Drops hist2d + scan_bins dispatches and blockHist traffic.

#define KLEN      262144      // 2^18
#define GX        512
#define GY        512
#define NCOILS    16
#define NBATCH    2
#define TBL_LEN   6145        // 6*1024+1
#define TBL_CTR   3072
#define PLANE     (GX*GY)
#define NPTS      (NBATCH*KLEN)
#define NBINS     2048        // NBATCH * 32*32 tiles

typedef _Float16 half2_t __attribute__((ext_vector_type(2)));
struct alignas(16) H8 { half2_t h[4]; };   // 4 coils' (re,im) fp16 = 16 B

// ---------------------------------------------------------------------------
// ws layout (bytes). btot/cursor alias the osort region: they are dead
// before interp_sorted writes osort.
// ---------------------------------------------------------------------------
#define WS_XT       0                         // 33554432  fp16 grid records
#define WS_OSORT    33554432                  // 33554432  fp16 sorted outputs
#define WS_BTOT     33554432                  //     8192  u32 [NBINS]
#define WS_CUR      (33554432+8192)           //     8192  u32 [NBINS]
#define WS_INV      69206016                  //  2097152  u32 pos per point id
#define WS_SOM      71303168                  //  4194304  float2 om per pos
#define WS_TOTAL    75497472

__device__ inline int point_bin(float om0, float om1)
{
    const float TWO_PI = 6.2831853071795864769f;
    const float tm0 = (om0 * 512.0f) / TWO_PI;
    const float tm1 = (om1 * 512.0f) / TWO_PI;
    const int cx = ((int)floorf(tm0)) & 511;
    const int cy = ((int)floorf(tm1)) & 511;
    return ((cx >> 4) << 5) | (cy >> 4);      // [0, 1024)
}

// ---------------------------------------------------------------------------
// Transpose+downconvert via LDS; histogram fused in (1 point per thread,
// grid is exactly NPTS/256 blocks). btot must be zeroed beforehand
// (hipMemsetAsync); pass btot=nullptr to skip the histogram (middle path).
// ---------------------------------------------------------------------------
__global__ __launch_bounds__(256) void transpose_fp16(
    const float* __restrict__ x, float4* __restrict__ xt,
    const float* __restrict__ om, unsigned* __restrict__ btot)
{
    __shared__ float s[32][260];   // [plane][cell], pad 260 (16B-aligned rows)
    const int blk   = blockIdx.x;            // [0, NBATCH*PLANE/256)
    const int base  = blk * 256;
    const int b     = base >> 18;
    const int cell0 = base & (PLANE - 1);
    const int t     = threadIdx.x;

    // ---- fused histogram: one point per thread --------------------------
    if (btot != nullptr) {
        const int id = blk * 256 + t;        // [0, NPTS)
        const int hb = id >> 18, hm = id & (KLEN - 1);
        const float hom0 = om[(size_t)(hb * 2 + 0) * KLEN + hm];
        const float hom1 = om[(size_t)(hb * 2 + 1) * KLEN + hm];
        const int hg = (hb << 10) | point_bin(hom0, hom1);
        atomicAdd(&btot[hg], 1u);
    }

    // ---- transpose body --------------------------------------------------
    const float* xb = x + (size_t)b * 32 * PLANE + cell0;
#pragma unroll
    for (int i = 0; i < 8; ++i) {
        const int fidx = i * 256 + t;        // [0, 2048)
        const int pl = fidx >> 6;            // wave-uniform plane
        const int j  = fidx & 63;
        const float4 v = *(const float4*)(xb + (size_t)pl * PLANE + j * 4);
        *(float4*)&s[pl][j * 4] = v;
    }
    __syncthreads();
#pragma unroll
    for (int i = 0; i < 4; ++i) {
        const int chunk = i * 256 + t;       // [0, 1024)
        const int cell = chunk >> 2, q = chunk & 3;
        H8 rec;
#pragma unroll
        for (int cc = 0; cc < 4; ++cc) {
            const int c = q * 4 + cc;
            rec.h[cc] = half2_t{(_Float16)s[2 * c][cell],
                                (_Float16)s[2 * c + 1][cell]};
        }
        xt[((size_t)b * PLANE + cell0 + cell) * 4 + q] = *(const float4*)&rec;
    }
}

// ---------------------------------------------------------------------------
// Single-block exclusive scan of the 2048 bin totals -> cursor.
// ---------------------------------------------------------------------------
__global__ __launch_bounds__(256) void scan_kernel(
    const unsigned* __restrict__ hist, unsigned* __restrict__ cursor)
{
    __shared__ unsigned partial[256];
    const int t = threadIdx.x;
    unsigned v[8];
    unsigned s = 0;
#pragma unroll
    for (int i = 0; i < 8; ++i) { v[i] = hist[t * 8 + i]; s += v[i]; }
    partial[t] = s;
    __syncthreads();
    for (int d = 1; d < 256; d <<= 1) {
        unsigned x = (t >= d) ? partial[t - d] : 0u;
        __syncthreads();
        partial[t] += x;
        __syncthreads();
    }
    unsigned base = (t > 0) ? partial[t - 1] : 0u;   // exclusive
#pragma unroll
    for (int i = 0; i < 8; ++i) { cursor[t * 8 + i] = base; base += v[i]; }
}

// ---------------------------------------------------------------------------
// Scatter: position via global atomic rank on the scanned cursor. Within-bin
// order is arrival-order (nondeterministic) -- harmless, inv[] records it.
// ---------------------------------------------------------------------------
__global__ __launch_bounds__(256) void scatter2(
    const float*    __restrict__ om,
    unsigned*       __restrict__ cursor,
    unsigned*       __restrict__ inv,
    float2*         __restrict__ som)
{
    const int id = blockIdx.x * blockDim.x + threadIdx.x;   // [0, NPTS)
    const int b = id >> 18, m = id & (KLEN - 1);
    const float om0 = om[(size_t)(b * 2 + 0) * KLEN + m];
    const float om1 = om[(size_t)(b * 2 + 1) * KLEN + m];
    const int g = (b << 10) | point_bin(om0, om1);
    const unsigned pos = atomicAdd(&cursor[g], 1u);
    inv[id]  = pos;
    som[pos] = make_float2(om0, om1);
}

// ---------------------------------------------------------------------------
// Main interp over sorted positions: ONE thread per point, all 16 coils.
// Coefficients/tables/phase computed once per point (was 4x redundant).
// Gathers are tile-local (16x16 bins -> ~28 KB neighborhood, L1/L2-hot).
// ---------------------------------------------------------------------------
__global__ __launch_bounds__(256) void interp_sorted(
    const float2*   __restrict__ som,
    const float*    __restrict__ t0,
    const float*    __restrict__ t1,
    const float4*   __restrict__ xt,
    float4*         __restrict__ osort)
{
    const int pos = blockIdx.x * blockDim.x + threadIdx.x;  // [0, NPTS)
    const int b   = pos >> 18;            // batch-major bins, KLEN pts/batch

    const float2 o = som[pos];
    const float om0 = o.x, om1 = o.y;

    const float TWO_PI = 6.2831853071795864769f;
    const float tm0 = (om0 * 512.0f) / TWO_PI;
    const float tm1 = (om1 * 512.0f) / TWO_PI;

    const float koff0 = 1.0f + floorf(tm0 - 3.0f);
    const float koff1 = 1.0f + floorf(tm1 - 3.0f);
    const int   k0    = (int)koff0;
    const int   k1    = (int)koff1;

    float c0r[6], c0i[6], c1r[6], c1i[6];
    int   coff[6];
#pragma unroll
    for (int j = 0; j < 6; ++j) {
        const float g0 = koff0 + (float)j;
        const int   d0 = (int)rintf((tm0 - g0) * 1024.0f) + TBL_CTR;
        c0r[j] = t0[d0];
        c0i[j] = t0[TBL_LEN + d0];
        const float g1 = koff1 + (float)j;
        const int   d1 = (int)rintf((tm1 - g1) * 1024.0f) + TBL_CTR;
        c1r[j] = t1[d1];
        c1i[j] = t1[TBL_LEN + d1];
        coff[j] = ((k1 + j) & 511) << 2;   // chunk offset within row
    }

    const float4* rec = xt + ((size_t)b << 20);   // b * PLANE * 4 chunks
    float acr[16], aci[16];
#pragma unroll
    for (int c = 0; c < 16; ++c) { acr[c] = 0.f; aci[c] = 0.f; }

#pragma unroll
    for (int j0 = 0; j0 < 6; ++j0) {
        const int roff = (k0 + j0) & 511;
        const float4* rowp = rec + ((size_t)roff << 11);     // *512*4
        const float ar = c0r[j0], ai = c0i[j0];
#pragma unroll
        for (int j1 = 0; j1 < 6; ++j1) {
            const float br = c1r[j1], bi = c1i[j1];
            const float cr = ar * br - ai * bi;
            const float ci = ar * bi + ai * br;
            const half2_t p1 = {(_Float16)cr, (_Float16)(-ci)}; // real acc
            const half2_t p2 = {(_Float16)ci, (_Float16)cr};    // imag acc
            const float4* cp = rowp + coff[j1];
            float4 raw[4];
#pragma unroll
            for (int q = 0; q < 4; ++q) raw[q] = cp[q];
#pragma unroll
            for (int q = 0; q < 4; ++q) {
                const H8 v = *(const H8*)&raw[q];
#pragma unroll
                for (int cc = 0; cc < 4; ++cc) {
                    const int coil = q * 4 + cc;
                    acr[coil] = __builtin_amdgcn_fdot2(v.h[cc], p1, acr[coil], false);
                    aci[coil] = __builtin_amdgcn_fdot2(v.h[cc], p2, aci[coil], false);
                }
            }
        }
    }

    // phase twist: exp(i * (om0+om1)*128)
    const float ph = om0 * 128.0f + om1 * 128.0f;
    const float s = sinf(ph), c = cosf(ph);

    float4* op = osort + (size_t)pos * 4;
#pragma unroll
    for (int q = 0; q < 4; ++q) {
        H8 outrec;
#pragma unroll
        for (int cc = 0; cc < 4; ++cc) {
            const int coil = q * 4 + cc;
            const float yr = acr[coil] * c - aci[coil] * s;
            const float yi = acr[coil] * s + aci[coil] * c;
            outrec.h[cc] = half2_t{(_Float16)yr, (_Float16)yi};
        }
        op[q] = *(const float4*)&outrec;
    }
}

// ---------------------------------------------------------------------------
// Unsort: thread per point id; gather 64 B record from osort, store coalesced
// into final (b,c,ri,m) layout.
// ---------------------------------------------------------------------------
__global__ __launch_bounds__(256) void unsort_kernel(
    const unsigned* __restrict__ inv,
    const float4*   __restrict__ osort,
    float*          __restrict__ out)
{
    const int id = blockIdx.x * blockDim.x + threadIdx.x;   // [0, NPTS)
    const int b = id >> 18, m = id & (KLEN - 1);
    const unsigned pos = inv[id];
    const float4* rp = osort + (size_t)pos * 4;

    float4 raw[4];
#pragma unroll
    for (int q = 0; q < 4; ++q) raw[q] = rp[q];

    float* ob = out + (size_t)b * NCOILS * 2 * KLEN + m;
#pragma unroll
    for (int q = 0; q < 4; ++q) {
        const H8 v = *(const H8*)&raw[q];
#pragma unroll
        for (int cc = 0; cc < 4; ++cc) {
            const int coil = q * 4 + cc;
            ob[(size_t)(2 * coil)     * KLEN] = (float)v.h[cc].x;
            ob[(size_t)(2 * coil + 1) * KLEN] = (float)v.h[cc].y;
        }
    }
}

// ---------------------------------------------------------------------------
// Middle path (ws >= xt only): direct-order interp (4 lanes/point, as R6).
// ---------------------------------------------------------------------------
__global__ __launch_bounds__(256) void interp_direct(
    const float*  __restrict__ om,
    const float*  __restrict__ t0,
    const float*  __restrict__ t1,
    const float4* __restrict__ xt,
    float*        __restrict__ out)
{
    const int tid  = blockIdx.x * blockDim.x + threadIdx.x;
    const int lane = tid & 3;
    const int p    = tid >> 2;
    const int b    = p >> 18;
    const int m    = p & (KLEN - 1);

    const float om0 = om[(size_t)(b * 2 + 0) * KLEN + m];
    const float om1 = om[(size_t)(b * 2 + 1) * KLEN + m];

    const float TWO_PI = 6.2831853071795864769f;
    const float tm0 = (om0 * 512.0f) / TWO_PI;
    const float tm1 = (om1 * 512.0f) / TWO_PI;
    const float koff0 = 1.0f + floorf(tm0 - 3.0f);
    const float koff1 = 1.0f + floorf(tm1 - 3.0f);
    const int k0 = (int)koff0, k1 = (int)koff1;

    float c0r[6], c0i[6], c1r[6], c1i[6];
    int coff[6];
#pragma unroll
    for (int j = 0; j < 6; ++j) {
        const float g0 = koff0 + (float)j;
        const int d0 = (int)rintf((tm0 - g0) * 1024.0f) + TBL_CTR;
        c0r[j] = t0[d0];
        c0i[j] = t0[TBL_LEN + d0];
        const float g1 = koff1 + (float)j;
        const int d1 = (int)rintf((tm1 - g1) * 1024.0f) + TBL_CTR;
        c1r[j] = t1[d1];
        c1i[j] = t1[TBL_LEN + d1];
        coff[j] = ((k1 + j) & 511) << 2;
    }

    const float4* rec = xt + ((size_t)b << 20);
    float acr[4] = {0.f, 0.f, 0.f, 0.f};
    float aci[4] = {0.f, 0.f, 0.f, 0.f};
#pragma unroll
    for (int j0 = 0; j0 < 6; ++j0) {
        const int roff = (k0 + j0) & 511;
        const float4* rowp = rec + ((size_t)roff << 11) + lane;
        const float ar = c0r[j0], ai = c0i[j0];
#pragma unroll
        for (int j1 = 0; j1 < 6; ++j1) {
            const float br = c1r[j1], bi = c1i[j1];
            const float cr = ar * br - ai * bi;
            const float ci = ar * bi + ai * br;
            const half2_t p1 = {(_Float16)cr, (_Float16)(-ci)};
            const half2_t p2 = {(_Float16)ci, (_Float16)cr};
            const float4 raw = rowp[coff[j1]];
            const H8 v = *(const H8*)&raw;
#pragma unroll
            for (int cc = 0; cc < 4; ++cc) {
                acr[cc] = __builtin_amdgcn_fdot2(v.h[cc], p1, acr[cc], false);
                aci[cc] = __builtin_amdgcn_fdot2(v.h[cc], p2, aci[cc], false);
            }
        }
    }

    const float ph = om0 * 128.0f + om1 * 128.0f;
    const float s = sinf(ph), c = cosf(ph);
#pragma unroll
    for (int cc = 0; cc < 4; ++cc) {
        const float yr = acr[cc] * c - aci[cc] * s;
        const float yi = acr[cc] * s + aci[cc] * c;
        const int coil = lane * 4 + cc;
        const size_t ob = ((size_t)(b * NCOILS + coil) * 2) * KLEN + m;
        out[ob]        = yr;
        out[ob + KLEN] = yi;
    }
}

// ---------------------------------------------------------------------------
// Fallback (tiny ws): one thread per point, original layout.
// ---------------------------------------------------------------------------
__global__ __launch_bounds__(256) void interp_fallback(
    const float* __restrict__ om,
    const float* __restrict__ t0,
    const float* __restrict__ t1,
    const float* __restrict__ x,
    float*       __restrict__ out)
{
    const int p = blockIdx.x * blockDim.x + threadIdx.x;
    const int b = p >> 18;
    const int m = p & (KLEN - 1);

    const float om0 = om[(size_t)(b * 2 + 0) * KLEN + m];
    const float om1 = om[(size_t)(b * 2 + 1) * KLEN + m];
    const float TWO_PI = 6.2831853071795864769f;
    const float tm0 = (om0 * 512.0f) / TWO_PI;
    const float tm1 = (om1 * 512.0f) / TWO_PI;
    const float koff0 = 1.0f + floorf(tm0 - 3.0f);
    const float koff1 = 1.0f + floorf(tm1 - 3.0f);
    const int k0 = (int)koff0, k1 = (int)koff1;

    float c0r[6], c0i[6], c1r[6], c1i[6];
    int roff[6], coff[6];
#pragma unroll
    for (int j = 0; j < 6; ++j) {
        const float g0 = koff0 + (float)j;
        const int d0 = (int)rintf((tm0 - g0) * 1024.0f) + TBL_CTR;
        c0r[j] = t0[d0];
        c0i[j] = t0[TBL_LEN + d0];
        const float g1 = koff1 + (float)j;
        const int d1 = (int)rintf((tm1 - g1) * 1024.0f) + TBL_CTR;
        c1r[j] = t1[d1];
        c1i[j] = t1[TBL_LEN + d1];
        roff[j] = (k0 + j) & 511;
        coff[j] = (k1 + j) & 511;
    }

    float accr[NCOILS], acci[NCOILS];
#pragma unroll
    for (int c = 0; c < NCOILS; ++c) { accr[c] = 0.f; acci[c] = 0.f; }

    const float* xb = x + (size_t)b * NCOILS * 2 * PLANE;
#pragma unroll
    for (int j0 = 0; j0 < 6; ++j0) {
        const float ar = c0r[j0], ai = c0i[j0];
        const int rb = roff[j0] * GY;
#pragma unroll
        for (int j1 = 0; j1 < 6; ++j1) {
            const float br = c1r[j1], bi = c1i[j1];
            const float cr = ar * br - ai * bi;
            const float ci = ar * bi + ai * br;
            const int ai_idx = rb + coff[j1];
#pragma unroll
            for (int c = 0; c < NCOILS; ++c) {
                const float dr = xb[(size_t)c * (2 * PLANE) + ai_idx];
                const float di = xb[(size_t)c * (2 * PLANE) + PLANE + ai_idx];
                accr[c] += cr * dr - ci * di;
                acci[c] += cr * di + ci * dr;
            }
        }
    }

    const float ph = om0 * 128.0f + om1 * 128.0f;
    const float s = sinf(ph), c = cosf(ph);
#pragma unroll
    for (int cc = 0; cc < NCOILS; ++cc) {
        const float yr = accr[cc] * c - acci[cc] * s;
        const float yi = accr[cc] * s + acci[cc] * c;
        size_t ob = ((size_t)(b * NCOILS + cc) * 2) * KLEN + m;
        out[ob]        = yr;
        out[ob + KLEN] = yi;
    }
}

extern "C" void kernel_launch(void* const* d_in, const int* in_sizes, int n_in,
                              void* d_out, int out_size, void* d_ws, size_t ws_size,
                              hipStream_t stream)
{
    const float* x  = (const float*)d_in[0];
    const float* om = (const float*)d_in[1];
    const float* t0 = (const float*)d_in[2];
    const float* t1 = (const float*)d_in[3];
    float* out = (float*)d_out;

    char* ws = (char*)d_ws;
    const size_t xt_bytes = (size_t)NBATCH * PLANE * NCOILS * 2 * sizeof(__half);

    if (ws_size >= (size_t)WS_TOTAL) {
        float4*   xt     = (float4*)(ws + WS_XT);
        float4*   osort  = (float4*)(ws + WS_OSORT);
        unsigned* btot   = (unsigned*)(ws + WS_BTOT);
        unsigned* cur    = (unsigned*)(ws + WS_CUR);
        unsigned* inv    = (unsigned*)(ws + WS_INV);
        float2*   som    = (float2*)(ws + WS_SOM);

        hipMemsetAsync(btot, 0, NBINS * sizeof(unsigned), stream);
        transpose_fp16<<<NBATCH * PLANE / 256, 256, 0, stream>>>(x, xt, om, btot);
        scan_kernel<<<1, 256, 0, stream>>>(btot, cur);
        scatter2<<<NPTS / 256, 256, 0, stream>>>(om, cur, inv, som);
        interp_sorted<<<NPTS / 256, 256, 0, stream>>>(som, t0, t1, xt, osort);
        unsort_kernel<<<NPTS / 256, 256, 0, stream>>>(inv, osort, out);
    } else if (ws_size >= xt_bytes) {
        float4* xt = (float4*)ws;
        transpose_fp16<<<NBATCH * PLANE / 256, 256, 0, stream>>>(x, xt, om, nullptr);
        interp_direct<<<NPTS * 4 / 256, 256, 0, stream>>>(om, t0, t1, xt, out);
    } else {
        interp_fallback<<<NPTS / 256, 256, 0, stream>>>(om, t0, t1, x, out);
    }
}

// Round 2
// 415.242 us; speedup vs baseline: 1.4040x; 1.4040x over previous
//
#include <hip/hip_runtime.h>
#include <hip/hip_fp16.h>

// KbInterpForw: table-based KB NUFFT interpolation, forward.
// x: (2,16,2,512,512) f32, om: (2,2,262144) f32, tables: (2,6145) f32 each.
// out: (2,16,2,262144) f32.
//
// R8 (post-mortem of R7's spill disaster):
//  - R7's 1-thread-per-point (16 coils) hit VGPR=256 + ~580 MB scratch spill
//    traffic (WRITE_SIZE 446 MB vs 32 MB of real output). Reverted to a
//    2-lanes-per-point x 8-coils split: setup (tables, 36 coeff products,
//    cvt/pack, sincos) is 2x redundant instead of R6's 4x, but register
//    footprint stays ~R6+12 VGPRs -> no spills.
//  - Collapsed 2-pass sort from R7 kept: histogram fused into transpose_fp16,
//    scatter ranks via global atomicAdd on scanned cursor. Within-bin order
//    nondeterministic; inv[] records the exact permutation, output unchanged.

#define KLEN      262144      // 2^18
#define GX        512
#define GY        512
#define NCOILS    16
#define NBATCH    2
#define TBL_LEN   6145        // 6*1024+1
#define TBL_CTR   3072
#define PLANE     (GX*GY)
#define NPTS      (NBATCH*KLEN)
#define NBINS     2048        // NBATCH * 32*32 tiles

typedef _Float16 half2_t __attribute__((ext_vector_type(2)));
struct alignas(16) H8 { half2_t h[4]; };   // 4 coils' (re,im) fp16 = 16 B

// ---------------------------------------------------------------------------
// ws layout (bytes). btot/cursor alias the osort region: they are dead
// before interp_sorted writes osort.
// ---------------------------------------------------------------------------
#define WS_XT       0                         // 33554432  fp16 grid records
#define WS_OSORT    33554432                  // 33554432  fp16 sorted outputs
#define WS_BTOT     33554432                  //     8192  u32 [NBINS]
#define WS_CUR      (33554432+8192)           //     8192  u32 [NBINS]
#define WS_INV      69206016                  //  2097152  u32 pos per point id
#define WS_SOM      71303168                  //  4194304  float2 om per pos
#define WS_TOTAL    75497472

__device__ inline int point_bin(float om0, float om1)
{
    const float TWO_PI = 6.2831853071795864769f;
    const float tm0 = (om0 * 512.0f) / TWO_PI;
    const float tm1 = (om1 * 512.0f) / TWO_PI;
    const int cx = ((int)floorf(tm0)) & 511;
    const int cy = ((int)floorf(tm1)) & 511;
    return ((cx >> 4) << 5) | (cy >> 4);      // [0, 1024)
}

// ---------------------------------------------------------------------------
// Transpose+downconvert via LDS; histogram fused in (1 point per thread,
// grid is exactly NPTS/256 blocks). btot must be zeroed beforehand
// (hipMemsetAsync); pass btot=nullptr to skip the histogram (middle path).
// ---------------------------------------------------------------------------
__global__ __launch_bounds__(256) void transpose_fp16(
    const float* __restrict__ x, float4* __restrict__ xt,
    const float* __restrict__ om, unsigned* __restrict__ btot)
{
    __shared__ float s[32][260];   // [plane][cell], pad 260 (16B-aligned rows)
    const int blk   = blockIdx.x;            // [0, NBATCH*PLANE/256)
    const int base  = blk * 256;
    const int b     = base >> 18;
    const int cell0 = base & (PLANE - 1);
    const int t     = threadIdx.x;

    // ---- fused histogram: one point per thread --------------------------
    if (btot != nullptr) {
        const int id = blk * 256 + t;        // [0, NPTS)
        const int hb = id >> 18, hm = id & (KLEN - 1);
        const float hom0 = om[(size_t)(hb * 2 + 0) * KLEN + hm];
        const float hom1 = om[(size_t)(hb * 2 + 1) * KLEN + hm];
        const int hg = (hb << 10) | point_bin(hom0, hom1);
        atomicAdd(&btot[hg], 1u);
    }

    // ---- transpose body --------------------------------------------------
    const float* xb = x + (size_t)b * 32 * PLANE + cell0;
#pragma unroll
    for (int i = 0; i < 8; ++i) {
        const int fidx = i * 256 + t;        // [0, 2048)
        const int pl = fidx >> 6;            // wave-uniform plane
        const int j  = fidx & 63;
        const float4 v = *(const float4*)(xb + (size_t)pl * PLANE + j * 4);
        *(float4*)&s[pl][j * 4] = v;
    }
    __syncthreads();
#pragma unroll
    for (int i = 0; i < 4; ++i) {
        const int chunk = i * 256 + t;       // [0, 1024)
        const int cell = chunk >> 2, q = chunk & 3;
        H8 rec;
#pragma unroll
        for (int cc = 0; cc < 4; ++cc) {
            const int c = q * 4 + cc;
            rec.h[cc] = half2_t{(_Float16)s[2 * c][cell],
                                (_Float16)s[2 * c + 1][cell]};
        }
        xt[((size_t)b * PLANE + cell0 + cell) * 4 + q] = *(const float4*)&rec;
    }
}

// ---------------------------------------------------------------------------
// Single-block exclusive scan of the 2048 bin totals -> cursor.
// ---------------------------------------------------------------------------
__global__ __launch_bounds__(256) void scan_kernel(
    const unsigned* __restrict__ hist, unsigned* __restrict__ cursor)
{
    __shared__ unsigned partial[256];
    const int t = threadIdx.x;
    unsigned v[8];
    unsigned s = 0;
#pragma unroll
    for (int i = 0; i < 8; ++i) { v[i] = hist[t * 8 + i]; s += v[i]; }
    partial[t] = s;
    __syncthreads();
    for (int d = 1; d < 256; d <<= 1) {
        unsigned x = (t >= d) ? partial[t - d] : 0u;
        __syncthreads();
        partial[t] += x;
        __syncthreads();
    }
    unsigned base = (t > 0) ? partial[t - 1] : 0u;   // exclusive
#pragma unroll
    for (int i = 0; i < 8; ++i) { cursor[t * 8 + i] = base; base += v[i]; }
}

// ---------------------------------------------------------------------------
// Scatter: position via global atomic rank on the scanned cursor. Within-bin
// order is arrival-order (nondeterministic) -- harmless, inv[] records it.
// ---------------------------------------------------------------------------
__global__ __launch_bounds__(256) void scatter2(
    const float*    __restrict__ om,
    unsigned*       __restrict__ cursor,
    unsigned*       __restrict__ inv,
    float2*         __restrict__ som)
{
    const int id = blockIdx.x * blockDim.x + threadIdx.x;   // [0, NPTS)
    const int b = id >> 18, m = id & (KLEN - 1);
    const float om0 = om[(size_t)(b * 2 + 0) * KLEN + m];
    const float om1 = om[(size_t)(b * 2 + 1) * KLEN + m];
    const int g = (b << 10) | point_bin(om0, om1);
    const unsigned pos = atomicAdd(&cursor[g], 1u);
    inv[id]  = pos;
    som[pos] = make_float2(om0, om1);
}

// ---------------------------------------------------------------------------
// Main interp over sorted positions: 2 lanes per point, lane owns 8 coils
// (chunks q = 2*lane, 2*lane+1). Setup is 2x redundant (vs R6's 4x) at
// +~12 VGPR over R6 -- no spills (R7's 1-lane/16-coil variant spilled).
// Gathers are tile-local (16x16 bins -> ~28 KB neighborhood, L1/L2-hot).
// ---------------------------------------------------------------------------
__global__ __launch_bounds__(256) void interp_sorted(
    const float2*   __restrict__ som,
    const float*    __restrict__ t0,
    const float*    __restrict__ t1,
    const float4*   __restrict__ xt,
    float4*         __restrict__ osort)
{
    const int tid  = blockIdx.x * blockDim.x + threadIdx.x;
    const int lane = tid & 1;
    const int pos  = tid >> 1;            // sorted position in [0, NPTS)
    const int b    = pos >> 18;           // batch-major bins, KLEN pts/batch

    const float2 o = som[pos];
    const float om0 = o.x, om1 = o.y;

    const float TWO_PI = 6.2831853071795864769f;
    const float tm0 = (om0 * 512.0f) / TWO_PI;
    const float tm1 = (om1 * 512.0f) / TWO_PI;

    const float koff0 = 1.0f + floorf(tm0 - 3.0f);
    const float koff1 = 1.0f + floorf(tm1 - 3.0f);
    const int   k0    = (int)koff0;
    const int   k1    = (int)koff1;

    float c0r[6], c0i[6], c1r[6], c1i[6];
    int   coff[6];
#pragma unroll
    for (int j = 0; j < 6; ++j) {
        const float g0 = koff0 + (float)j;
        const int   d0 = (int)rintf((tm0 - g0) * 1024.0f) + TBL_CTR;
        c0r[j] = t0[d0];
        c0i[j] = t0[TBL_LEN + d0];
        const float g1 = koff1 + (float)j;
        const int   d1 = (int)rintf((tm1 - g1) * 1024.0f) + TBL_CTR;
        c1r[j] = t1[d1];
        c1i[j] = t1[TBL_LEN + d1];
        coff[j] = ((k1 + j) & 511) << 2;   // chunk offset within row
    }

    // lane's 2 chunks (8 coils) of each 4-chunk record
    const float4* rec = xt + ((size_t)b << 20) + 2 * lane;
    float acr[8], aci[8];
#pragma unroll
    for (int c = 0; c < 8; ++c) { acr[c] = 0.f; aci[c] = 0.f; }

#pragma unroll
    for (int j0 = 0; j0 < 6; ++j0) {
        const int roff = (k0 + j0) & 511;
        const float4* rowp = rec + ((size_t)roff << 11);     // *512*4
        const float ar = c0r[j0], ai = c0i[j0];
#pragma unroll
        for (int j1 = 0; j1 < 6; ++j1) {
            const float br = c1r[j1], bi = c1i[j1];
            const float cr = ar * br - ai * bi;
            const float ci = ar * bi + ai * br;
            const half2_t p1 = {(_Float16)cr, (_Float16)(-ci)}; // real acc
            const half2_t p2 = {(_Float16)ci, (_Float16)cr};    // imag acc
            const float4* cp = rowp + coff[j1];
            const float4 raw0 = cp[0];
            const float4 raw1 = cp[1];
            const H8 v0 = *(const H8*)&raw0;
            const H8 v1 = *(const H8*)&raw1;
#pragma unroll
            for (int cc = 0; cc < 4; ++cc) {
                acr[cc]     = __builtin_amdgcn_fdot2(v0.h[cc], p1, acr[cc],     false);
                aci[cc]     = __builtin_amdgcn_fdot2(v0.h[cc], p2, aci[cc],     false);
                acr[4 + cc] = __builtin_amdgcn_fdot2(v1.h[cc], p1, acr[4 + cc], false);
                aci[4 + cc] = __builtin_amdgcn_fdot2(v1.h[cc], p2, aci[4 + cc], false);
            }
        }
    }

    // phase twist: exp(i * (om0+om1)*128)
    const float ph = om0 * 128.0f + om1 * 128.0f;
    const float s = sinf(ph), c = cosf(ph);

    float4* op = osort + (size_t)pos * 4 + 2 * lane;
#pragma unroll
    for (int q = 0; q < 2; ++q) {
        H8 outrec;
#pragma unroll
        for (int cc = 0; cc < 4; ++cc) {
            const int a = q * 4 + cc;
            const float yr = acr[a] * c - aci[a] * s;
            const float yi = acr[a] * s + aci[a] * c;
            outrec.h[cc] = half2_t{(_Float16)yr, (_Float16)yi};
        }
        op[q] = *(const float4*)&outrec;
    }
}

// ---------------------------------------------------------------------------
// Unsort: thread per point id; gather 64 B record from osort, store coalesced
// into final (b,c,ri,m) layout.
// ---------------------------------------------------------------------------
__global__ __launch_bounds__(256) void unsort_kernel(
    const unsigned* __restrict__ inv,
    const float4*   __restrict__ osort,
    float*          __restrict__ out)
{
    const int id = blockIdx.x * blockDim.x + threadIdx.x;   // [0, NPTS)
    const int b = id >> 18, m = id & (KLEN - 1);
    const unsigned pos = inv[id];
    const float4* rp = osort + (size_t)pos * 4;

    float4 raw[4];
#pragma unroll
    for (int q = 0; q < 4; ++q) raw[q] = rp[q];

    float* ob = out + (size_t)b * NCOILS * 2 * KLEN + m;
#pragma unroll
    for (int q = 0; q < 4; ++q) {
        const H8 v = *(const H8*)&raw[q];
#pragma unroll
        for (int cc = 0; cc < 4; ++cc) {
            const int coil = q * 4 + cc;
            ob[(size_t)(2 * coil)     * KLEN] = (float)v.h[cc].x;
            ob[(size_t)(2 * coil + 1) * KLEN] = (float)v.h[cc].y;
        }
    }
}

// ---------------------------------------------------------------------------
// Middle path (ws >= xt only): direct-order interp (4 lanes/point, as R6).
// ---------------------------------------------------------------------------
__global__ __launch_bounds__(256) void interp_direct(
    const float*  __restrict__ om,
    const float*  __restrict__ t0,
    const float*  __restrict__ t1,
    const float4* __restrict__ xt,
    float*        __restrict__ out)
{
    const int tid  = blockIdx.x * blockDim.x + threadIdx.x;
    const int lane = tid & 3;
    const int p    = tid >> 2;
    const int b    = p >> 18;
    const int m    = p & (KLEN - 1);

    const float om0 = om[(size_t)(b * 2 + 0) * KLEN + m];
    const float om1 = om[(size_t)(b * 2 + 1) * KLEN + m];

    const float TWO_PI = 6.2831853071795864769f;
    const float tm0 = (om0 * 512.0f) / TWO_PI;
    const float tm1 = (om1 * 512.0f) / TWO_PI;
    const float koff0 = 1.0f + floorf(tm0 - 3.0f);
    const float koff1 = 1.0f + floorf(tm1 - 3.0f);
    const int k0 = (int)koff0, k1 = (int)koff1;

    float c0r[6], c0i[6], c1r[6], c1i[6];
    int coff[6];
#pragma unroll
    for (int j = 0; j < 6; ++j) {
        const float g0 = koff0 + (float)j;
        const int d0 = (int)rintf((tm0 - g0) * 1024.0f) + TBL_CTR;
        c0r[j] = t0[d0];
        c0i[j] = t0[TBL_LEN + d0];
        const float g1 = koff1 + (float)j;
        const int d1 = (int)rintf((tm1 - g1) * 1024.0f) + TBL_CTR;
        c1r[j] = t1[d1];
        c1i[j] = t1[TBL_LEN + d1];
        coff[j] = ((k1 + j) & 511) << 2;
    }

    const float4* rec = xt + ((size_t)b << 20);
    float acr[4] = {0.f, 0.f, 0.f, 0.f};
    float aci[4] = {0.f, 0.f, 0.f, 0.f};
#pragma unroll
    for (int j0 = 0; j0 < 6; ++j0) {
        const int roff = (k0 + j0) & 511;
        const float4* rowp = rec + ((size_t)roff << 11) + lane;
        const float ar = c0r[j0], ai = c0i[j0];
#pragma unroll
        for (int j1 = 0; j1 < 6; ++j1) {
            const float br = c1r[j1], bi = c1i[j1];
            const float cr = ar * br - ai * bi;
            const float ci = ar * bi + ai * br;
            const half2_t p1 = {(_Float16)cr, (_Float16)(-ci)};
            const half2_t p2 = {(_Float16)ci, (_Float16)cr};
            const float4 raw = rowp[coff[j1]];
            const H8 v = *(const H8*)&raw;
#pragma unroll
            for (int cc = 0; cc < 4; ++cc) {
                acr[cc] = __builtin_amdgcn_fdot2(v.h[cc], p1, acr[cc], false);
                aci[cc] = __builtin_amdgcn_fdot2(v.h[cc], p2, aci[cc], false);
            }
        }
    }

    const float ph = om0 * 128.0f + om1 * 128.0f;
    const float s = sinf(ph), c = cosf(ph);
#pragma unroll
    for (int cc = 0; cc < 4; ++cc) {
        const float yr = acr[cc] * c - aci[cc] * s;
        const float yi = acr[cc] * s + aci[cc] * c;
        const int coil = lane * 4 + cc;
        const size_t ob = ((size_t)(b * NCOILS + coil) * 2) * KLEN + m;
        out[ob]        = yr;
        out[ob + KLEN] = yi;
    }
}

// ---------------------------------------------------------------------------
// Fallback (tiny ws): one thread per point, original layout.
// ---------------------------------------------------------------------------
__global__ __launch_bounds__(256) void interp_fallback(
    const float* __restrict__ om,
    const float* __restrict__ t0,
    const float* __restrict__ t1,
    const float* __restrict__ x,
    float*       __restrict__ out)
{
    const int p = blockIdx.x * blockDim.x + threadIdx.x;
    const int b = p >> 18;
    const int m = p & (KLEN - 1);

    const float om0 = om[(size_t)(b * 2 + 0) * KLEN + m];
    const float om1 = om[(size_t)(b * 2 + 1) * KLEN + m];
    const float TWO_PI = 6.2831853071795864769f;
    const float tm0 = (om0 * 512.0f) / TWO_PI;
    const float tm1 = (om1 * 512.0f) / TWO_PI;
    const float koff0 = 1.0f + floorf(tm0 - 3.0f);
    const float koff1 = 1.0f + floorf(tm1 - 3.0f);
    const int k0 = (int)koff0, k1 = (int)koff1;

    float c0r[6], c0i[6], c1r[6], c1i[6];
    int roff[6], coff[6];
#pragma unroll
    for (int j = 0; j < 6; ++j) {
        const float g0 = koff0 + (float)j;
        const int d0 = (int)rintf((tm0 - g0) * 1024.0f) + TBL_CTR;
        c0r[j] = t0[d0];
        c0i[j] = t0[TBL_LEN + d0];
        const float g1 = koff1 + (float)j;
        const int d1 = (int)rintf((tm1 - g1) * 1024.0f) + TBL_CTR;
        c1r[j] = t1[d1];
        c1i[j] = t1[TBL_LEN + d1];
        roff[j] = (k0 + j) & 511;
        coff[j] = (k1 + j) & 511;
    }

    float accr[NCOILS], acci[NCOILS];
#pragma unroll
    for (int c = 0; c < NCOILS; ++c) { accr[c] = 0.f; acci[c] = 0.f; }

    const float* xb = x + (size_t)b * NCOILS * 2 * PLANE;
#pragma unroll
    for (int j0 = 0; j0 < 6; ++j0) {
        const float ar = c0r[j0], ai = c0i[j0];
        const int rb = roff[j0] * GY;
#pragma unroll
        for (int j1 = 0; j1 < 6; ++j1) {
            const float br = c1r[j1], bi = c1i[j1];
            const float cr = ar * br - ai * bi;
            const float ci = ar * bi + ai * br;
            const int ai_idx = rb + coff[j1];
#pragma unroll
            for (int c = 0; c < NCOILS; ++c) {
                const float dr = xb[(size_t)c * (2 * PLANE) + ai_idx];
                const float di = xb[(size_t)c * (2 * PLANE) + PLANE + ai_idx];
                accr[c] += cr * dr - ci * di;
                acci[c] += cr * di + ci * dr;
            }
        }
    }

    const float ph = om0 * 128.0f + om1 * 128.0f;
    const float s = sinf(ph), c = cosf(ph);
#pragma unroll
    for (int cc = 0; cc < NCOILS; ++cc) {
        const float yr = accr[cc] * c - acci[cc] * s;
        const float yi = accr[cc] * s + acci[cc] * c;
        size_t ob = ((size_t)(b * NCOILS + cc) * 2) * KLEN + m;
        out[ob]        = yr;
        out[ob + KLEN] = yi;
    }
}

extern "C" void kernel_launch(void* const* d_in, const int* in_sizes, int n_in,
                              void* d_out, int out_size, void* d_ws, size_t ws_size,
                              hipStream_t stream)
{
    const float* x  = (const float*)d_in[0];
    const float* om = (const float*)d_in[1];
    const float* t0 = (const float*)d_in[2];
    const float* t1 = (const float*)d_in[3];
    float* out = (float*)d_out;

    char* ws = (char*)d_ws;
    const size_t xt_bytes = (size_t)NBATCH * PLANE * NCOILS * 2 * sizeof(__half);

    if (ws_size >= (size_t)WS_TOTAL) {
        float4*   xt     = (float4*)(ws + WS_XT);
        float4*   osort  = (float4*)(ws + WS_OSORT);
        unsigned* btot   = (unsigned*)(ws + WS_BTOT);
        unsigned* cur    = (unsigned*)(ws + WS_CUR);
        unsigned* inv    = (unsigned*)(ws + WS_INV);
        float2*   som    = (float2*)(ws + WS_SOM);

        hipMemsetAsync(btot, 0, NBINS * sizeof(unsigned), stream);
        transpose_fp16<<<NBATCH * PLANE / 256, 256, 0, stream>>>(x, xt, om, btot);
        scan_kernel<<<1, 256, 0, stream>>>(btot, cur);
        scatter2<<<NPTS / 256, 256, 0, stream>>>(om, cur, inv, som);
        interp_sorted<<<NPTS * 2 / 256, 256, 0, stream>>>(som, t0, t1, xt, osort);
        unsort_kernel<<<NPTS / 256, 256, 0, stream>>>(inv, osort, out);
    } else if (ws_size >= xt_bytes) {
        float4* xt = (float4*)ws;
        transpose_fp16<<<NBATCH * PLANE / 256, 256, 0, stream>>>(x, xt, om, nullptr);
        interp_direct<<<NPTS * 4 / 256, 256, 0, stream>>>(om, t0, t1, xt, out);
    } else {
        interp_fallback<<<NPTS / 256, 256, 0, stream>>>(om, t0, t1, x, out);
    }
}

// Round 3
// 387.112 us; speedup vs baseline: 1.5060x; 1.0727x over previous
//
#include <hip/hip_runtime.h>
#include <hip/hip_fp16.h>

// KbInterpForw: table-based KB NUFFT interpolation, forward.
// x: (2,16,2,512,512) f32, om: (2,2,262144) f32, tables: (2,6145) f32 each.
// out: (2,16,2,262144) f32.
//
// R9:
//  - Restored R6's deterministic LDS-histogram sort (hist2d/scan_bins/scan/
//    scatter2). R8's global-atomic variant cost ~140 us extra (1M device-
//    scope atomics).
//  - interp is now PER-BIN: one block per bin stages the bin's 21x21-record
//    halo tile (441 x 64 B) into LDS at stride 80 B (period-8 bank phases ->
//    scattered ds_read_b128 ~2-way instead of 8-way conflicts). All 36
//    gathers per point become low-latency LDS reads; R6's version was
//    latency-bound on L1-miss gathers (FETCH 102 MB vs 32 MB of xt).
//  - 4 lanes/point x 4 coils kept (R8 showed fewer/fatter threads loses to
//    latency). __launch_bounds__(256,4) pins VGPR <= 128 -> 4 blocks/CU,
//    matching the 35.3 KB LDS cap.
//  - bbase moved to the unaliased gap after osort so interp can read bin
//    ranges (count = bbase[bin+1]-bbase[bin]) while writing osort.

#define KLEN      262144      // 2^18
#define GX        512
#define GY        512
#define NCOILS    16
#define NBATCH    2
#define TBL_LEN   6145        // 6*1024+1
#define TBL_CTR   3072
#define PLANE     (GX*GY)
#define NPTS      (NBATCH*KLEN)
#define NBINS     2048        // NBATCH * 32*32 tiles
#define NBLK      256         // sort blocks
#define PPB       2048        // points per sort block (NPTS/NBLK)

#define TROWS     21          // 16 + 5 halo
#define TQ        5           // float4 slots per record in LDS (4 used + 1 pad)

typedef _Float16 half2_t __attribute__((ext_vector_type(2)));
struct alignas(16) H8 { half2_t h[4]; };   // 4 coils' (re,im) fp16 = 16 B

// ---------------------------------------------------------------------------
// ws layout (bytes). blockHist/binTotal alias the osort region (dead before
// interp writes osort). binBase lives in the 2 MB gap after osort: it must
// survive INTO interp (bin ranges).
// ---------------------------------------------------------------------------
#define WS_XT       0                         // 33554432  fp16 grid records
#define WS_OSORT    33554432                  // 33554432  fp16 sorted outputs
#define WS_BHIST    33554432                  //  2097152  u32 [NBINS][NBLK] (alias osort)
#define WS_BTOT     (33554432+2097152)        //     8192  u32 [NBINS]       (alias osort)
#define WS_BBASE    67108864                  //     8192  u32 [NBINS]  NOT aliased
#define WS_INV      69206016                  //  2097152  u32 pos per point id
#define WS_SOM      71303168                  //  4194304  float2 om per pos
#define WS_TOTAL    75497472

__device__ inline int point_bin(float om0, float om1)
{
    const float TWO_PI = 6.2831853071795864769f;
    const float tm0 = (om0 * 512.0f) / TWO_PI;
    const float tm1 = (om1 * 512.0f) / TWO_PI;
    const int cx = ((int)floorf(tm0)) & 511;
    const int cy = ((int)floorf(tm1)) & 511;
    return ((cx >> 4) << 5) | (cy >> 4);      // [0, 1024)
}

// ---------------------------------------------------------------------------
// Transpose+downconvert via LDS. Block handles 256 consecutive cells.
// ---------------------------------------------------------------------------
__global__ __launch_bounds__(256) void transpose_fp16(
    const float* __restrict__ x, float4* __restrict__ xt)
{
    __shared__ float s[32][260];   // [plane][cell], pad 260 (16B-aligned rows)
    const int blk   = blockIdx.x;            // [0, NBATCH*PLANE/256)
    const int base  = blk * 256;
    const int b     = base >> 18;
    const int cell0 = base & (PLANE - 1);
    const int t     = threadIdx.x;

    const float* xb = x + (size_t)b * 32 * PLANE + cell0;
#pragma unroll
    for (int i = 0; i < 8; ++i) {
        const int fidx = i * 256 + t;        // [0, 2048)
        const int pl = fidx >> 6;            // wave-uniform plane
        const int j  = fidx & 63;
        const float4 v = *(const float4*)(xb + (size_t)pl * PLANE + j * 4);
        *(float4*)&s[pl][j * 4] = v;
    }
    __syncthreads();
#pragma unroll
    for (int i = 0; i < 4; ++i) {
        const int chunk = i * 256 + t;       // [0, 1024)
        const int cell = chunk >> 2, q = chunk & 3;
        H8 rec;
#pragma unroll
        for (int cc = 0; cc < 4; ++cc) {
            const int c = q * 4 + cc;
            rec.h[cc] = half2_t{(_Float16)s[2 * c][cell],
                                (_Float16)s[2 * c + 1][cell]};
        }
        xt[((size_t)b * PLANE + cell0 + cell) * 4 + q] = *(const float4*)&rec;
    }
}

// ---------------------------------------------------------------------------
// Sort pass 1: per-block LDS histogram -> blockHist[bin][blk] (bin-major).
// ---------------------------------------------------------------------------
__global__ __launch_bounds__(256) void hist2d(
    const float* __restrict__ om, unsigned* __restrict__ blockHist)
{
    __shared__ unsigned h[NBINS];
    const int t = threadIdx.x, blk = blockIdx.x;
#pragma unroll
    for (int i = 0; i < NBINS / 256; ++i) h[t + i * 256] = 0u;
    __syncthreads();
#pragma unroll
    for (int i = 0; i < PPB / 256; ++i) {
        const int id = blk * PPB + i * 256 + t;
        const int b = id >> 18, m = id & (KLEN - 1);
        const float om0 = om[(size_t)(b * 2 + 0) * KLEN + m];
        const float om1 = om[(size_t)(b * 2 + 1) * KLEN + m];
        const int g = (b << 10) | point_bin(om0, om1);
        atomicAdd(&h[g], 1u);
    }
    __syncthreads();
#pragma unroll
    for (int i = 0; i < NBINS / 256; ++i) {
        const int bin = t + i * 256;
        blockHist[(size_t)bin * NBLK + blk] = h[bin];   // strided once
    }
}

// ---------------------------------------------------------------------------
// Sort pass 2: per-bin exclusive scan over NBLK block counts + per-bin total.
// ---------------------------------------------------------------------------
__global__ __launch_bounds__(256) void scan_bins(
    unsigned* __restrict__ blockHist, unsigned* __restrict__ binTotal)
{
    __shared__ unsigned partial[256];
    const int bin = blockIdx.x;
    const int t = threadIdx.x;
    const unsigned v = blockHist[(size_t)bin * NBLK + t];   // coalesced 1 KB
    partial[t] = v;
    __syncthreads();
    for (int d = 1; d < 256; d <<= 1) {
        unsigned x = (t >= d) ? partial[t - d] : 0u;
        __syncthreads();
        partial[t] += x;
        __syncthreads();
    }
    blockHist[(size_t)bin * NBLK + t] = partial[t] - v;     // exclusive
    if (t == 255) binTotal[bin] = partial[255];
}

// ---------------------------------------------------------------------------
// Sort pass 3: single-block exclusive scan of the 2048 bin totals.
// ---------------------------------------------------------------------------
__global__ __launch_bounds__(256) void scan_kernel(
    const unsigned* __restrict__ hist, unsigned* __restrict__ cursor)
{
    __shared__ unsigned partial[256];
    const int t = threadIdx.x;
    unsigned v[8];
    unsigned s = 0;
#pragma unroll
    for (int i = 0; i < 8; ++i) { v[i] = hist[t * 8 + i]; s += v[i]; }
    partial[t] = s;
    __syncthreads();
    for (int d = 1; d < 256; d <<= 1) {
        unsigned x = (t >= d) ? partial[t - d] : 0u;
        __syncthreads();
        partial[t] += x;
        __syncthreads();
    }
    unsigned base = (t > 0) ? partial[t - 1] : 0u;   // exclusive
#pragma unroll
    for (int i = 0; i < 8; ++i) { cursor[t * 8 + i] = base; base += v[i]; }
}

// ---------------------------------------------------------------------------
// Sort pass 4: final positions. LDS atomics give local rank within
// (block, bin); position = binBase + blockHist + rank.
// ---------------------------------------------------------------------------
__global__ __launch_bounds__(256) void scatter2(
    const float*    __restrict__ om,
    const unsigned* __restrict__ blockHist,
    const unsigned* __restrict__ binBase,
    unsigned* __restrict__ inv,
    float2* __restrict__ som)
{
    __shared__ unsigned h[NBINS];
    const int t = threadIdx.x, blk = blockIdx.x;
#pragma unroll
    for (int i = 0; i < NBINS / 256; ++i) h[t + i * 256] = 0u;
    __syncthreads();
#pragma unroll
    for (int i = 0; i < PPB / 256; ++i) {
        const int id = blk * PPB + i * 256 + t;
        const int b = id >> 18, m = id & (KLEN - 1);
        const float om0 = om[(size_t)(b * 2 + 0) * KLEN + m];
        const float om1 = om[(size_t)(b * 2 + 1) * KLEN + m];
        const int g = (b << 10) | point_bin(om0, om1);
        const unsigned r = atomicAdd(&h[g], 1u);
        const unsigned pos = binBase[g] + blockHist[(size_t)g * NBLK + blk] + r;
        inv[id]  = pos;
        som[pos] = make_float2(om0, om1);
    }
}

// ---------------------------------------------------------------------------
// Main interp: ONE BLOCK PER BIN. Stage the bin's 21x21-record halo tile
// into LDS (stride TQ=5 float4 per record -> period-8 bank phases), then all
// gathers are ds_read_b128. 4 lanes per point, lane owns chunk q=lane.
// ---------------------------------------------------------------------------
__global__ __launch_bounds__(256, 4) void interp_bins(
    const float2*   __restrict__ som,
    const float*    __restrict__ t0,
    const float*    __restrict__ t1,
    const float4*   __restrict__ xt,
    const unsigned* __restrict__ bbase,
    float4*         __restrict__ osort)
{
    __shared__ float4 tile[TROWS * TROWS * TQ];   // 2205 f4 = 35280 B
    const int bin = blockIdx.x;
    const int t   = threadIdx.x;
    const int b   = bin >> 10;
    const int cx0 = ((bin >> 5) & 31) << 4;
    const int cy0 = (bin & 31) << 4;

    const unsigned p0  = bbase[bin];
    const unsigned p1e = (bin == NBINS - 1) ? (unsigned)NPTS : bbase[bin + 1];
    const int cnt = (int)(p1e - p0);

    // ---- stage halo tile: 441 records x 4 chunks, coalesced rows --------
    const float4* rec = xt + ((size_t)b << 20);   // b * PLANE * 4 chunks
    for (int f = t; f < TROWS * TROWS * 4; f += 256) {
        const int r = f >> 2, q = f & 3;
        const int row = r / TROWS;                // const-div -> magic mul
        const int col = r - row * TROWS;
        const int gr = (cx0 - 2 + row) & 511;
        const int gc = (cy0 - 2 + col) & 511;
        tile[r * TQ + q] = rec[(((size_t)((gr << 9) | gc)) << 2) + q];
    }
    __syncthreads();

    const int lane = t & 3;
    for (int base = 0; base < cnt; base += 64) {
        const int idx = base + (t >> 2);
        if (idx >= cnt) continue;
        const int pos = (int)p0 + idx;

        const float2 o = som[pos];
        const float om0 = o.x, om1 = o.y;

        const float TWO_PI = 6.2831853071795864769f;
        const float tm0 = (om0 * 512.0f) / TWO_PI;
        const float tm1 = (om1 * 512.0f) / TWO_PI;

        const float koff0 = 1.0f + floorf(tm0 - 3.0f);
        const float koff1 = 1.0f + floorf(tm1 - 3.0f);
        const int   k0    = (int)koff0;
        const int   k1    = (int)koff1;

        float c0r[6], c0i[6], c1r[6], c1i[6];
        int   loff[6];
#pragma unroll
        for (int j = 0; j < 6; ++j) {
            const float g0 = koff0 + (float)j;
            const int   d0 = (int)rintf((tm0 - g0) * 1024.0f) + TBL_CTR;
            c0r[j] = t0[d0];
            c0i[j] = t0[TBL_LEN + d0];
            const float g1 = koff1 + (float)j;
            const int   d1 = (int)rintf((tm1 - g1) * 1024.0f) + TBL_CTR;
            c1r[j] = t1[d1];
            c1i[j] = t1[TBL_LEN + d1];
            loff[j] = ((k1 + j - cy0 + 2) & 511) * TQ;   // in [0, 20]*TQ
        }

        float acr[4] = {0.f, 0.f, 0.f, 0.f};
        float aci[4] = {0.f, 0.f, 0.f, 0.f};
#pragma unroll
        for (int j0 = 0; j0 < 6; ++j0) {
            const int rIdx = (k0 + j0 - cx0 + 2) & 511;  // in [0, 20]
            const float4* rowp = &tile[rIdx * (TROWS * TQ) + lane];
            const float ar = c0r[j0], ai = c0i[j0];
#pragma unroll
            for (int j1 = 0; j1 < 6; ++j1) {
                const float br = c1r[j1], bi = c1i[j1];
                const float cr = ar * br - ai * bi;
                const float ci = ar * bi + ai * br;
                const half2_t p1 = {(_Float16)cr, (_Float16)(-ci)}; // real acc
                const half2_t p2 = {(_Float16)ci, (_Float16)cr};    // imag acc
                const float4 raw = rowp[loff[j1]];
                const H8 v = *(const H8*)&raw;
#pragma unroll
                for (int cc = 0; cc < 4; ++cc) {
                    acr[cc] = __builtin_amdgcn_fdot2(v.h[cc], p1, acr[cc], false);
                    aci[cc] = __builtin_amdgcn_fdot2(v.h[cc], p2, aci[cc], false);
                }
            }
        }

        // phase twist: exp(i * (om0+om1)*128)
        const float ph = om0 * 128.0f + om1 * 128.0f;
        const float s = sinf(ph), c = cosf(ph);

        H8 outrec;
#pragma unroll
        for (int cc = 0; cc < 4; ++cc) {
            const float yr = acr[cc] * c - aci[cc] * s;
            const float yi = acr[cc] * s + aci[cc] * c;
            outrec.h[cc] = half2_t{(_Float16)yr, (_Float16)yi};
        }
        osort[(size_t)pos * 4 + lane] = *(const float4*)&outrec;   // coalesced
    }
}

// ---------------------------------------------------------------------------
// Unsort: thread per point id; gather 64 B record from osort, store coalesced
// into final (b,c,ri,m) layout.
// ---------------------------------------------------------------------------
__global__ __launch_bounds__(256) void unsort_kernel(
    const unsigned* __restrict__ inv,
    const float4*   __restrict__ osort,
    float*          __restrict__ out)
{
    const int id = blockIdx.x * blockDim.x + threadIdx.x;   // [0, NPTS)
    const int b = id >> 18, m = id & (KLEN - 1);
    const unsigned pos = inv[id];
    const float4* rp = osort + (size_t)pos * 4;

    float4 raw[4];
#pragma unroll
    for (int q = 0; q < 4; ++q) raw[q] = rp[q];

    float* ob = out + (size_t)b * NCOILS * 2 * KLEN + m;
#pragma unroll
    for (int q = 0; q < 4; ++q) {
        const H8 v = *(const H8*)&raw[q];
#pragma unroll
        for (int cc = 0; cc < 4; ++cc) {
            const int coil = q * 4 + cc;
            ob[(size_t)(2 * coil)     * KLEN] = (float)v.h[cc].x;
            ob[(size_t)(2 * coil + 1) * KLEN] = (float)v.h[cc].y;
        }
    }
}

// ---------------------------------------------------------------------------
// Middle path (ws >= xt only): direct-order interp (4 lanes/point).
// ---------------------------------------------------------------------------
__global__ __launch_bounds__(256) void interp_direct(
    const float*  __restrict__ om,
    const float*  __restrict__ t0,
    const float*  __restrict__ t1,
    const float4* __restrict__ xt,
    float*        __restrict__ out)
{
    const int tid  = blockIdx.x * blockDim.x + threadIdx.x;
    const int lane = tid & 3;
    const int p    = tid >> 2;
    const int b    = p >> 18;
    const int m    = p & (KLEN - 1);

    const float om0 = om[(size_t)(b * 2 + 0) * KLEN + m];
    const float om1 = om[(size_t)(b * 2 + 1) * KLEN + m];

    const float TWO_PI = 6.2831853071795864769f;
    const float tm0 = (om0 * 512.0f) / TWO_PI;
    const float tm1 = (om1 * 512.0f) / TWO_PI;
    const float koff0 = 1.0f + floorf(tm0 - 3.0f);
    const float koff1 = 1.0f + floorf(tm1 - 3.0f);
    const int k0 = (int)koff0, k1 = (int)koff1;

    float c0r[6], c0i[6], c1r[6], c1i[6];
    int coff[6];
#pragma unroll
    for (int j = 0; j < 6; ++j) {
        const float g0 = koff0 + (float)j;
        const int d0 = (int)rintf((tm0 - g0) * 1024.0f) + TBL_CTR;
        c0r[j] = t0[d0];
        c0i[j] = t0[TBL_LEN + d0];
        const float g1 = koff1 + (float)j;
        const int d1 = (int)rintf((tm1 - g1) * 1024.0f) + TBL_CTR;
        c1r[j] = t1[d1];
        c1i[j] = t1[TBL_LEN + d1];
        coff[j] = ((k1 + j) & 511) << 2;
    }

    const float4* rec = xt + ((size_t)b << 20);
    float acr[4] = {0.f, 0.f, 0.f, 0.f};
    float aci[4] = {0.f, 0.f, 0.f, 0.f};
#pragma unroll
    for (int j0 = 0; j0 < 6; ++j0) {
        const int roff = (k0 + j0) & 511;
        const float4* rowp = rec + ((size_t)roff << 11) + lane;
        const float ar = c0r[j0], ai = c0i[j0];
#pragma unroll
        for (int j1 = 0; j1 < 6; ++j1) {
            const float br = c1r[j1], bi = c1i[j1];
            const float cr = ar * br - ai * bi;
            const float ci = ar * bi + ai * br;
            const half2_t p1 = {(_Float16)cr, (_Float16)(-ci)};
            const half2_t p2 = {(_Float16)ci, (_Float16)cr};
            const float4 raw = rowp[coff[j1]];
            const H8 v = *(const H8*)&raw;
#pragma unroll
            for (int cc = 0; cc < 4; ++cc) {
                acr[cc] = __builtin_amdgcn_fdot2(v.h[cc], p1, acr[cc], false);
                aci[cc] = __builtin_amdgcn_fdot2(v.h[cc], p2, aci[cc], false);
            }
        }
    }

    const float ph = om0 * 128.0f + om1 * 128.0f;
    const float s = sinf(ph), c = cosf(ph);
#pragma unroll
    for (int cc = 0; cc < 4; ++cc) {
        const float yr = acr[cc] * c - aci[cc] * s;
        const float yi = acr[cc] * s + aci[cc] * c;
        const int coil = lane * 4 + cc;
        const size_t ob = ((size_t)(b * NCOILS + coil) * 2) * KLEN + m;
        out[ob]        = yr;
        out[ob + KLEN] = yi;
    }
}

// ---------------------------------------------------------------------------
// Fallback (tiny ws): one thread per point, original layout.
// ---------------------------------------------------------------------------
__global__ __launch_bounds__(256) void interp_fallback(
    const float* __restrict__ om,
    const float* __restrict__ t0,
    const float* __restrict__ t1,
    const float* __restrict__ x,
    float*       __restrict__ out)
{
    const int p = blockIdx.x * blockDim.x + threadIdx.x;
    const int b = p >> 18;
    const int m = p & (KLEN - 1);

    const float om0 = om[(size_t)(b * 2 + 0) * KLEN + m];
    const float om1 = om[(size_t)(b * 2 + 1) * KLEN + m];
    const float TWO_PI = 6.2831853071795864769f;
    const float tm0 = (om0 * 512.0f) / TWO_PI;
    const float tm1 = (om1 * 512.0f) / TWO_PI;
    const float koff0 = 1.0f + floorf(tm0 - 3.0f);
    const float koff1 = 1.0f + floorf(tm1 - 3.0f);
    const int k0 = (int)koff0, k1 = (int)koff1;

    float c0r[6], c0i[6], c1r[6], c1i[6];
    int roff[6], coff[6];
#pragma unroll
    for (int j = 0; j < 6; ++j) {
        const float g0 = koff0 + (float)j;
        const int d0 = (int)rintf((tm0 - g0) * 1024.0f) + TBL_CTR;
        c0r[j] = t0[d0];
        c0i[j] = t0[TBL_LEN + d0];
        const float g1 = koff1 + (float)j;
        const int d1 = (int)rintf((tm1 - g1) * 1024.0f) + TBL_CTR;
        c1r[j] = t1[d1];
        c1i[j] = t1[TBL_LEN + d1];
        roff[j] = (k0 + j) & 511;
        coff[j] = (k1 + j) & 511;
    }

    float accr[NCOILS], acci[NCOILS];
#pragma unroll
    for (int c = 0; c < NCOILS; ++c) { accr[c] = 0.f; acci[c] = 0.f; }

    const float* xb = x + (size_t)b * NCOILS * 2 * PLANE;
#pragma unroll
    for (int j0 = 0; j0 < 6; ++j0) {
        const float ar = c0r[j0], ai = c0i[j0];
        const int rb = roff[j0] * GY;
#pragma unroll
        for (int j1 = 0; j1 < 6; ++j1) {
            const float br = c1r[j1], bi = c1i[j1];
            const float cr = ar * br - ai * bi;
            const float ci = ar * bi + ai * br;
            const int ai_idx = rb + coff[j1];
#pragma unroll
            for (int c = 0; c < NCOILS; ++c) {
                const float dr = xb[(size_t)c * (2 * PLANE) + ai_idx];
                const float di = xb[(size_t)c * (2 * PLANE) + PLANE + ai_idx];
                accr[c] += cr * dr - ci * di;
                acci[c] += cr * di + ci * dr;
            }
        }
    }

    const float ph = om0 * 128.0f + om1 * 128.0f;
    const float s = sinf(ph), c = cosf(ph);
#pragma unroll
    for (int cc = 0; cc < NCOILS; ++cc) {
        const float yr = accr[cc] * c - acci[cc] * s;
        const float yi = accr[cc] * s + acci[cc] * c;
        size_t ob = ((size_t)(b * NCOILS + cc) * 2) * KLEN + m;
        out[ob]        = yr;
        out[ob + KLEN] = yi;
    }
}

extern "C" void kernel_launch(void* const* d_in, const int* in_sizes, int n_in,
                              void* d_out, int out_size, void* d_ws, size_t ws_size,
                              hipStream_t stream)
{
    const float* x  = (const float*)d_in[0];
    const float* om = (const float*)d_in[1];
    const float* t0 = (const float*)d_in[2];
    const float* t1 = (const float*)d_in[3];
    float* out = (float*)d_out;

    char* ws = (char*)d_ws;
    const size_t xt_bytes = (size_t)NBATCH * PLANE * NCOILS * 2 * sizeof(__half);

    if (ws_size >= (size_t)WS_TOTAL) {
        float4*   xt     = (float4*)(ws + WS_XT);
        float4*   osort  = (float4*)(ws + WS_OSORT);
        unsigned* bhist  = (unsigned*)(ws + WS_BHIST);
        unsigned* btot   = (unsigned*)(ws + WS_BTOT);
        unsigned* bbase  = (unsigned*)(ws + WS_BBASE);
        unsigned* inv    = (unsigned*)(ws + WS_INV);
        float2*   som    = (float2*)(ws + WS_SOM);

        transpose_fp16<<<NBATCH * PLANE / 256, 256, 0, stream>>>(x, xt);
        hist2d<<<NBLK, 256, 0, stream>>>(om, bhist);
        scan_bins<<<NBINS, 256, 0, stream>>>(bhist, btot);
        scan_kernel<<<1, 256, 0, stream>>>(btot, bbase);
        scatter2<<<NBLK, 256, 0, stream>>>(om, bhist, bbase, inv, som);
        interp_bins<<<NBINS, 256, 0, stream>>>(som, t0, t1, xt, bbase, osort);
        unsort_kernel<<<NPTS / 256, 256, 0, stream>>>(inv, osort, out);
    } else if (ws_size >= xt_bytes) {
        float4* xt = (float4*)ws;
        transpose_fp16<<<NBATCH * PLANE / 256, 256, 0, stream>>>(x, xt);
        interp_direct<<<NPTS * 4 / 256, 256, 0, stream>>>(om, t0, t1, xt, out);
    } else {
        interp_fallback<<<NPTS / 256, 256, 0, stream>>>(om, t0, t1, x, out);
    }
}

// Round 4
// 239.446 us; speedup vs baseline: 2.4348x; 1.6167x over previous
//
#include <hip/hip_runtime.h>
#include <hip/hip_fp16.h>

// KbInterpForw: table-based KB NUFFT interpolation, forward.
// x: (2,16,2,512,512) f32, om: (2,2,262144) f32, tables: (2,6145) f32 each.
// out: (2,16,2,262144) f32.
//
// R10 (post-mortem of R9):
//  - R9's per-bin LDS-tile structure was right, but __launch_bounds__(256,4)
//    clamped the allocator to VGPR=64 -> register-pressure spills: 677 MB
//    phantom WRITE / 353 MB phantom FETCH of scratch traffic, kernel became
//    scratch-BW-bound at 235 us. The pin was unnecessary: at the natural
//    ~120 VGPR the wave limit (4/SIMD) and the 35.3 KB LDS limit both give
//    4 blocks/CU. Fix: plain __launch_bounds__(256). No other changes.
//  - Structure: one block per bin stages the bin's 21x21-record halo tile
//    (441 x 64 B) into LDS at stride 80 B (period-8 bank phases), then all
//    36 gathers per point are ds_read_b128. 4 lanes/point x 4 coils.
//  - Deterministic 4-pass sort (R6) unchanged.

#define KLEN      262144      // 2^18
#define GX        512
#define GY        512
#define NCOILS    16
#define NBATCH    2
#define TBL_LEN   6145        // 6*1024+1
#define TBL_CTR   3072
#define PLANE     (GX*GY)
#define NPTS      (NBATCH*KLEN)
#define NBINS     2048        // NBATCH * 32*32 tiles
#define NBLK      256         // sort blocks
#define PPB       2048        // points per sort block (NPTS/NBLK)

#define TROWS     21          // 16 + 5 halo
#define TQ        5           // float4 slots per record in LDS (4 used + 1 pad)

typedef _Float16 half2_t __attribute__((ext_vector_type(2)));
struct alignas(16) H8 { half2_t h[4]; };   // 4 coils' (re,im) fp16 = 16 B

// ---------------------------------------------------------------------------
// ws layout (bytes). blockHist/binTotal alias the osort region (dead before
// interp writes osort). binBase lives in the unaliased gap after osort: it
// must survive INTO interp (bin ranges).
// ---------------------------------------------------------------------------
#define WS_XT       0                         // 33554432  fp16 grid records
#define WS_OSORT    33554432                  // 33554432  fp16 sorted outputs
#define WS_BHIST    33554432                  //  2097152  u32 [NBINS][NBLK] (alias osort)
#define WS_BTOT     (33554432+2097152)        //     8192  u32 [NBINS]       (alias osort)
#define WS_BBASE    67108864                  //     8192  u32 [NBINS]  NOT aliased
#define WS_INV      69206016                  //  2097152  u32 pos per point id
#define WS_SOM      71303168                  //  4194304  float2 om per pos
#define WS_TOTAL    75497472

__device__ inline int point_bin(float om0, float om1)
{
    const float TWO_PI = 6.2831853071795864769f;
    const float tm0 = (om0 * 512.0f) / TWO_PI;
    const float tm1 = (om1 * 512.0f) / TWO_PI;
    const int cx = ((int)floorf(tm0)) & 511;
    const int cy = ((int)floorf(tm1)) & 511;
    return ((cx >> 4) << 5) | (cy >> 4);      // [0, 1024)
}

// ---------------------------------------------------------------------------
// Transpose+downconvert via LDS. Block handles 256 consecutive cells.
// ---------------------------------------------------------------------------
__global__ __launch_bounds__(256) void transpose_fp16(
    const float* __restrict__ x, float4* __restrict__ xt)
{
    __shared__ float s[32][260];   // [plane][cell], pad 260 (16B-aligned rows)
    const int blk   = blockIdx.x;            // [0, NBATCH*PLANE/256)
    const int base  = blk * 256;
    const int b     = base >> 18;
    const int cell0 = base & (PLANE - 1);
    const int t     = threadIdx.x;

    const float* xb = x + (size_t)b * 32 * PLANE + cell0;
#pragma unroll
    for (int i = 0; i < 8; ++i) {
        const int fidx = i * 256 + t;        // [0, 2048)
        const int pl = fidx >> 6;            // wave-uniform plane
        const int j  = fidx & 63;
        const float4 v = *(const float4*)(xb + (size_t)pl * PLANE + j * 4);
        *(float4*)&s[pl][j * 4] = v;
    }
    __syncthreads();
#pragma unroll
    for (int i = 0; i < 4; ++i) {
        const int chunk = i * 256 + t;       // [0, 1024)
        const int cell = chunk >> 2, q = chunk & 3;
        H8 rec;
#pragma unroll
        for (int cc = 0; cc < 4; ++cc) {
            const int c = q * 4 + cc;
            rec.h[cc] = half2_t{(_Float16)s[2 * c][cell],
                                (_Float16)s[2 * c + 1][cell]};
        }
        xt[((size_t)b * PLANE + cell0 + cell) * 4 + q] = *(const float4*)&rec;
    }
}

// ---------------------------------------------------------------------------
// Sort pass 1: per-block LDS histogram -> blockHist[bin][blk] (bin-major).
// ---------------------------------------------------------------------------
__global__ __launch_bounds__(256) void hist2d(
    const float* __restrict__ om, unsigned* __restrict__ blockHist)
{
    __shared__ unsigned h[NBINS];
    const int t = threadIdx.x, blk = blockIdx.x;
#pragma unroll
    for (int i = 0; i < NBINS / 256; ++i) h[t + i * 256] = 0u;
    __syncthreads();
#pragma unroll
    for (int i = 0; i < PPB / 256; ++i) {
        const int id = blk * PPB + i * 256 + t;
        const int b = id >> 18, m = id & (KLEN - 1);
        const float om0 = om[(size_t)(b * 2 + 0) * KLEN + m];
        const float om1 = om[(size_t)(b * 2 + 1) * KLEN + m];
        const int g = (b << 10) | point_bin(om0, om1);
        atomicAdd(&h[g], 1u);
    }
    __syncthreads();
#pragma unroll
    for (int i = 0; i < NBINS / 256; ++i) {
        const int bin = t + i * 256;
        blockHist[(size_t)bin * NBLK + blk] = h[bin];   // strided once
    }
}

// ---------------------------------------------------------------------------
// Sort pass 2: per-bin exclusive scan over NBLK block counts + per-bin total.
// ---------------------------------------------------------------------------
__global__ __launch_bounds__(256) void scan_bins(
    unsigned* __restrict__ blockHist, unsigned* __restrict__ binTotal)
{
    __shared__ unsigned partial[256];
    const int bin = blockIdx.x;
    const int t = threadIdx.x;
    const unsigned v = blockHist[(size_t)bin * NBLK + t];   // coalesced 1 KB
    partial[t] = v;
    __syncthreads();
    for (int d = 1; d < 256; d <<= 1) {
        unsigned x = (t >= d) ? partial[t - d] : 0u;
        __syncthreads();
        partial[t] += x;
        __syncthreads();
    }
    blockHist[(size_t)bin * NBLK + t] = partial[t] - v;     // exclusive
    if (t == 255) binTotal[bin] = partial[255];
}

// ---------------------------------------------------------------------------
// Sort pass 3: single-block exclusive scan of the 2048 bin totals.
// ---------------------------------------------------------------------------
__global__ __launch_bounds__(256) void scan_kernel(
    const unsigned* __restrict__ hist, unsigned* __restrict__ cursor)
{
    __shared__ unsigned partial[256];
    const int t = threadIdx.x;
    unsigned v[8];
    unsigned s = 0;
#pragma unroll
    for (int i = 0; i < 8; ++i) { v[i] = hist[t * 8 + i]; s += v[i]; }
    partial[t] = s;
    __syncthreads();
    for (int d = 1; d < 256; d <<= 1) {
        unsigned x = (t >= d) ? partial[t - d] : 0u;
        __syncthreads();
        partial[t] += x;
        __syncthreads();
    }
    unsigned base = (t > 0) ? partial[t - 1] : 0u;   // exclusive
#pragma unroll
    for (int i = 0; i < 8; ++i) { cursor[t * 8 + i] = base; base += v[i]; }
}

// ---------------------------------------------------------------------------
// Sort pass 4: final positions. LDS atomics give local rank within
// (block, bin); position = binBase + blockHist + rank.
// ---------------------------------------------------------------------------
__global__ __launch_bounds__(256) void scatter2(
    const float*    __restrict__ om,
    const unsigned* __restrict__ blockHist,
    const unsigned* __restrict__ binBase,
    unsigned* __restrict__ inv,
    float2* __restrict__ som)
{
    __shared__ unsigned h[NBINS];
    const int t = threadIdx.x, blk = blockIdx.x;
#pragma unroll
    for (int i = 0; i < NBINS / 256; ++i) h[t + i * 256] = 0u;
    __syncthreads();
#pragma unroll
    for (int i = 0; i < PPB / 256; ++i) {
        const int id = blk * PPB + i * 256 + t;
        const int b = id >> 18, m = id & (KLEN - 1);
        const float om0 = om[(size_t)(b * 2 + 0) * KLEN + m];
        const float om1 = om[(size_t)(b * 2 + 1) * KLEN + m];
        const int g = (b << 10) | point_bin(om0, om1);
        const unsigned r = atomicAdd(&h[g], 1u);
        const unsigned pos = binBase[g] + blockHist[(size_t)g * NBLK + blk] + r;
        inv[id]  = pos;
        som[pos] = make_float2(om0, om1);
    }
}

// ---------------------------------------------------------------------------
// Main interp: ONE BLOCK PER BIN. Stage the bin's 21x21-record halo tile
// into LDS (stride TQ=5 float4 per record -> period-8 bank phases), then all
// gathers are ds_read_b128. 4 lanes per point, lane owns chunk q=lane.
// NOTE: no waves-per-EU pin -- R9's (256,4) forced VGPR=64 + scratch spills.
// ---------------------------------------------------------------------------
__global__ __launch_bounds__(256) void interp_bins(
    const float2*   __restrict__ som,
    const float*    __restrict__ t0,
    const float*    __restrict__ t1,
    const float4*   __restrict__ xt,
    const unsigned* __restrict__ bbase,
    float4*         __restrict__ osort)
{
    __shared__ float4 tile[TROWS * TROWS * TQ];   // 2205 f4 = 35280 B
    const int bin = blockIdx.x;
    const int t   = threadIdx.x;
    const int b   = bin >> 10;
    const int cx0 = ((bin >> 5) & 31) << 4;
    const int cy0 = (bin & 31) << 4;

    const unsigned p0  = bbase[bin];
    const unsigned p1e = (bin == NBINS - 1) ? (unsigned)NPTS : bbase[bin + 1];
    const int cnt = (int)(p1e - p0);

    // ---- stage halo tile: 441 records x 4 chunks, coalesced rows --------
    const float4* rec = xt + ((size_t)b << 20);   // b * PLANE * 4 chunks
    for (int f = t; f < TROWS * TROWS * 4; f += 256) {
        const int r = f >> 2, q = f & 3;
        const int row = r / TROWS;                // const-div -> magic mul
        const int col = r - row * TROWS;
        const int gr = (cx0 - 2 + row) & 511;
        const int gc = (cy0 - 2 + col) & 511;
        tile[r * TQ + q] = rec[(((size_t)((gr << 9) | gc)) << 2) + q];
    }
    __syncthreads();

    const int lane = t & 3;
    for (int base = 0; base < cnt; base += 64) {
        const int idx = base + (t >> 2);
        if (idx >= cnt) continue;
        const int pos = (int)p0 + idx;

        const float2 o = som[pos];
        const float om0 = o.x, om1 = o.y;

        const float TWO_PI = 6.2831853071795864769f;
        const float tm0 = (om0 * 512.0f) / TWO_PI;
        const float tm1 = (om1 * 512.0f) / TWO_PI;

        const float koff0 = 1.0f + floorf(tm0 - 3.0f);
        const float koff1 = 1.0f + floorf(tm1 - 3.0f);
        const int   k0    = (int)koff0;
        const int   k1    = (int)koff1;

        float c0r[6], c0i[6], c1r[6], c1i[6];
        int   loff[6];
#pragma unroll
        for (int j = 0; j < 6; ++j) {
            const float g0 = koff0 + (float)j;
            const int   d0 = (int)rintf((tm0 - g0) * 1024.0f) + TBL_CTR;
            c0r[j] = t0[d0];
            c0i[j] = t0[TBL_LEN + d0];
            const float g1 = koff1 + (float)j;
            const int   d1 = (int)rintf((tm1 - g1) * 1024.0f) + TBL_CTR;
            c1r[j] = t1[d1];
            c1i[j] = t1[TBL_LEN + d1];
            loff[j] = ((k1 + j - cy0 + 2) & 511) * TQ;   // in [0, 20]*TQ
        }

        float acr[4] = {0.f, 0.f, 0.f, 0.f};
        float aci[4] = {0.f, 0.f, 0.f, 0.f};
#pragma unroll
        for (int j0 = 0; j0 < 6; ++j0) {
            const int rIdx = (k0 + j0 - cx0 + 2) & 511;  // in [0, 20]
            const float4* rowp = &tile[rIdx * (TROWS * TQ) + lane];
            const float ar = c0r[j0], ai = c0i[j0];
#pragma unroll
            for (int j1 = 0; j1 < 6; ++j1) {
                const float br = c1r[j1], bi = c1i[j1];
                const float cr = ar * br - ai * bi;
                const float ci = ar * bi + ai * br;
                const half2_t p1 = {(_Float16)cr, (_Float16)(-ci)}; // real acc
                const half2_t p2 = {(_Float16)ci, (_Float16)cr};    // imag acc
                const float4 raw = rowp[loff[j1]];
                const H8 v = *(const H8*)&raw;
#pragma unroll
                for (int cc = 0; cc < 4; ++cc) {
                    acr[cc] = __builtin_amdgcn_fdot2(v.h[cc], p1, acr[cc], false);
                    aci[cc] = __builtin_amdgcn_fdot2(v.h[cc], p2, aci[cc], false);
                }
            }
        }

        // phase twist: exp(i * (om0+om1)*128)
        const float ph = om0 * 128.0f + om1 * 128.0f;
        const float s = sinf(ph), c = cosf(ph);

        H8 outrec;
#pragma unroll
        for (int cc = 0; cc < 4; ++cc) {
            const float yr = acr[cc] * c - aci[cc] * s;
            const float yi = acr[cc] * s + aci[cc] * c;
            outrec.h[cc] = half2_t{(_Float16)yr, (_Float16)yi};
        }
        osort[(size_t)pos * 4 + lane] = *(const float4*)&outrec;   // coalesced
    }
}

// ---------------------------------------------------------------------------
// Unsort: thread per point id; gather 64 B record from osort, store coalesced
// into final (b,c,ri,m) layout.
// ---------------------------------------------------------------------------
__global__ __launch_bounds__(256) void unsort_kernel(
    const unsigned* __restrict__ inv,
    const float4*   __restrict__ osort,
    float*          __restrict__ out)
{
    const int id = blockIdx.x * blockDim.x + threadIdx.x;   // [0, NPTS)
    const int b = id >> 18, m = id & (KLEN - 1);
    const unsigned pos = inv[id];
    const float4* rp = osort + (size_t)pos * 4;

    float4 raw[4];
#pragma unroll
    for (int q = 0; q < 4; ++q) raw[q] = rp[q];

    float* ob = out + (size_t)b * NCOILS * 2 * KLEN + m;
#pragma unroll
    for (int q = 0; q < 4; ++q) {
        const H8 v = *(const H8*)&raw[q];
#pragma unroll
        for (int cc = 0; cc < 4; ++cc) {
            const int coil = q * 4 + cc;
            ob[(size_t)(2 * coil)     * KLEN] = (float)v.h[cc].x;
            ob[(size_t)(2 * coil + 1) * KLEN] = (float)v.h[cc].y;
        }
    }
}

// ---------------------------------------------------------------------------
// Middle path (ws >= xt only): direct-order interp (4 lanes/point).
// ---------------------------------------------------------------------------
__global__ __launch_bounds__(256) void interp_direct(
    const float*  __restrict__ om,
    const float*  __restrict__ t0,
    const float*  __restrict__ t1,
    const float4* __restrict__ xt,
    float*        __restrict__ out)
{
    const int tid  = blockIdx.x * blockDim.x + threadIdx.x;
    const int lane = tid & 3;
    const int p    = tid >> 2;
    const int b    = p >> 18;
    const int m    = p & (KLEN - 1);

    const float om0 = om[(size_t)(b * 2 + 0) * KLEN + m];
    const float om1 = om[(size_t)(b * 2 + 1) * KLEN + m];

    const float TWO_PI = 6.2831853071795864769f;
    const float tm0 = (om0 * 512.0f) / TWO_PI;
    const float tm1 = (om1 * 512.0f) / TWO_PI;
    const float koff0 = 1.0f + floorf(tm0 - 3.0f);
    const float koff1 = 1.0f + floorf(tm1 - 3.0f);
    const int k0 = (int)koff0, k1 = (int)koff1;

    float c0r[6], c0i[6], c1r[6], c1i[6];
    int coff[6];
#pragma unroll
    for (int j = 0; j < 6; ++j) {
        const float g0 = koff0 + (float)j;
        const int d0 = (int)rintf((tm0 - g0) * 1024.0f) + TBL_CTR;
        c0r[j] = t0[d0];
        c0i[j] = t0[TBL_LEN + d0];
        const float g1 = koff1 + (float)j;
        const int d1 = (int)rintf((tm1 - g1) * 1024.0f) + TBL_CTR;
        c1r[j] = t1[d1];
        c1i[j] = t1[TBL_LEN + d1];
        coff[j] = ((k1 + j) & 511) << 2;
    }

    const float4* rec = xt + ((size_t)b << 20);
    float acr[4] = {0.f, 0.f, 0.f, 0.f};
    float aci[4] = {0.f, 0.f, 0.f, 0.f};
#pragma unroll
    for (int j0 = 0; j0 < 6; ++j0) {
        const int roff = (k0 + j0) & 511;
        const float4* rowp = rec + ((size_t)roff << 11) + lane;
        const float ar = c0r[j0], ai = c0i[j0];
#pragma unroll
        for (int j1 = 0; j1 < 6; ++j1) {
            const float br = c1r[j1], bi = c1i[j1];
            const float cr = ar * br - ai * bi;
            const float ci = ar * bi + ai * br;
            const half2_t p1 = {(_Float16)cr, (_Float16)(-ci)};
            const half2_t p2 = {(_Float16)ci, (_Float16)cr};
            const float4 raw = rowp[coff[j1]];
            const H8 v = *(const H8*)&raw;
#pragma unroll
            for (int cc = 0; cc < 4; ++cc) {
                acr[cc] = __builtin_amdgcn_fdot2(v.h[cc], p1, acr[cc], false);
                aci[cc] = __builtin_amdgcn_fdot2(v.h[cc], p2, aci[cc], false);
            }
        }
    }

    const float ph = om0 * 128.0f + om1 * 128.0f;
    const float s = sinf(ph), c = cosf(ph);
#pragma unroll
    for (int cc = 0; cc < 4; ++cc) {
        const float yr = acr[cc] * c - aci[cc] * s;
        const float yi = acr[cc] * s + aci[cc] * c;
        const int coil = lane * 4 + cc;
        const size_t ob = ((size_t)(b * NCOILS + coil) * 2) * KLEN + m;
        out[ob]        = yr;
        out[ob + KLEN] = yi;
    }
}

// ---------------------------------------------------------------------------
// Fallback (tiny ws): one thread per point, original layout.
// ---------------------------------------------------------------------------
__global__ __launch_bounds__(256) void interp_fallback(
    const float* __restrict__ om,
    const float* __restrict__ t0,
    const float* __restrict__ t1,
    const float* __restrict__ x,
    float*       __restrict__ out)
{
    const int p = blockIdx.x * blockDim.x + threadIdx.x;
    const int b = p >> 18;
    const int m = p & (KLEN - 1);

    const float om0 = om[(size_t)(b * 2 + 0) * KLEN + m];
    const float om1 = om[(size_t)(b * 2 + 1) * KLEN + m];
    const float TWO_PI = 6.2831853071795864769f;
    const float tm0 = (om0 * 512.0f) / TWO_PI;
    const float tm1 = (om1 * 512.0f) / TWO_PI;
    const float koff0 = 1.0f + floorf(tm0 - 3.0f);
    const float koff1 = 1.0f + floorf(tm1 - 3.0f);
    const int k0 = (int)koff0, k1 = (int)koff1;

    float c0r[6], c0i[6], c1r[6], c1i[6];
    int roff[6], coff[6];
#pragma unroll
    for (int j = 0; j < 6; ++j) {
        const float g0 = koff0 + (float)j;
        const int d0 = (int)rintf((tm0 - g0) * 1024.0f) + TBL_CTR;
        c0r[j] = t0[d0];
        c0i[j] = t0[TBL_LEN + d0];
        const float g1 = koff1 + (float)j;
        const int d1 = (int)rintf((tm1 - g1) * 1024.0f) + TBL_CTR;
        c1r[j] = t1[d1];
        c1i[j] = t1[TBL_LEN + d1];
        roff[j] = (k0 + j) & 511;
        coff[j] = (k1 + j) & 511;
    }

    float accr[NCOILS], acci[NCOILS];
#pragma unroll
    for (int c = 0; c < NCOILS; ++c) { accr[c] = 0.f; acci[c] = 0.f; }

    const float* xb = x + (size_t)b * NCOILS * 2 * PLANE;
#pragma unroll
    for (int j0 = 0; j0 < 6; ++j0) {
        const float ar = c0r[j0], ai = c0i[j0];
        const int rb = roff[j0] * GY;
#pragma unroll
        for (int j1 = 0; j1 < 6; ++j1) {
            const float br = c1r[j1], bi = c1i[j1];
            const float cr = ar * br - ai * bi;
            const float ci = ar * bi + ai * br;
            const int ai_idx = rb + coff[j1];
#pragma unroll
            for (int c = 0; c < NCOILS; ++c) {
                const float dr = xb[(size_t)c * (2 * PLANE) + ai_idx];
                const float di = xb[(size_t)c * (2 * PLANE) + PLANE + ai_idx];
                accr[c] += cr * dr - ci * di;
                acci[c] += cr * di + ci * dr;
            }
        }
    }

    const float ph = om0 * 128.0f + om1 * 128.0f;
    const float s = sinf(ph), c = cosf(ph);
#pragma unroll
    for (int cc = 0; cc < NCOILS; ++cc) {
        const float yr = accr[cc] * c - acci[cc] * s;
        const float yi = accr[cc] * s + acci[cc] * c;
        size_t ob = ((size_t)(b * NCOILS + cc) * 2) * KLEN + m;
        out[ob]        = yr;
        out[ob + KLEN] = yi;
    }
}

extern "C" void kernel_launch(void* const* d_in, const int* in_sizes, int n_in,
                              void* d_out, int out_size, void* d_ws, size_t ws_size,
                              hipStream_t stream)
{
    const float* x  = (const float*)d_in[0];
    const float* om = (const float*)d_in[1];
    const float* t0 = (const float*)d_in[2];
    const float* t1 = (const float*)d_in[3];
    float* out = (float*)d_out;

    char* ws = (char*)d_ws;
    const size_t xt_bytes = (size_t)NBATCH * PLANE * NCOILS * 2 * sizeof(__half);

    if (ws_size >= (size_t)WS_TOTAL) {
        float4*   xt     = (float4*)(ws + WS_XT);
        float4*   osort  = (float4*)(ws + WS_OSORT);
        unsigned* bhist  = (unsigned*)(ws + WS_BHIST);
        unsigned* btot   = (unsigned*)(ws + WS_BTOT);
        unsigned* bbase  = (unsigned*)(ws + WS_BBASE);
        unsigned* inv    = (unsigned*)(ws + WS_INV);
        float2*   som    = (float2*)(ws + WS_SOM);

        transpose_fp16<<<NBATCH * PLANE / 256, 256, 0, stream>>>(x, xt);
        hist2d<<<NBLK, 256, 0, stream>>>(om, bhist);
        scan_bins<<<NBINS, 256, 0, stream>>>(bhist, btot);
        scan_kernel<<<1, 256, 0, stream>>>(btot, bbase);
        scatter2<<<NBLK, 256, 0, stream>>>(om, bhist, bbase, inv, som);
        interp_bins<<<NBINS, 256, 0, stream>>>(som, t0, t1, xt, bbase, osort);
        unsort_kernel<<<NPTS / 256, 256, 0, stream>>>(inv, osort, out);
    } else if (ws_size >= xt_bytes) {
        float4* xt = (float4*)ws;
        transpose_fp16<<<NBATCH * PLANE / 256, 256, 0, stream>>>(x, xt);
        interp_direct<<<NPTS * 4 / 256, 256, 0, stream>>>(om, t0, t1, xt, out);
    } else {
        interp_fallback<<<NPTS / 256, 256, 0, stream>>>(om, t0, t1, x, out);
    }
}

// Round 5
// 221.715 us; speedup vs baseline: 2.6295x; 1.0800x over previous
//
#include <hip/hip_runtime.h>
#include <hip/hip_fp16.h>

// KbInterpForw: table-based KB NUFFT interpolation, forward.
// x: (2,16,2,512,512) f32, om: (2,2,262144) f32, tables: (2,6145) f32 each.
// out: (2,16,2,262144) f32.
//
// R11 (on R10's 239 us):
//  - Evidence R6 vs R10: swapping cache gathers for LDS gathers changed
//    nothing (89 vs 92 us, VALUBusy ~52% both) -> interp is VALU-ISSUE bound.
//    So: cut instructions.
//  - DPP quad-share of the coefficient stream: the 4 lanes of a point are a
//    hardware quad. Lane q computes the (cr,ci)->(p1,p2) pair for j1=q (and
//    j1=q+4 for q<2); v_mov_b32_dpp quad_perm broadcasts the owner's packed
//    pair. ~30 inst/j0 instead of ~54. Bit-identical numerics (owner runs
//    the same f32 expression every lane ran before).
//  - Native __sinf/__cosf (v_sin/v_cos; |ph|<=128 rev, in HW range) replaces
//    the precise libm polynomial (~60-90 inst/lane).
//  - scan_kernel dispatch deleted: scatter2 and interp_bins redundantly scan
//    the 2048-entry btot (8 KB, L2-hot) in LDS at block start. btot moved to
//    the non-aliased region (osort is written while interp still needs it).

#define KLEN      262144      // 2^18
#define GX        512
#define GY        512
#define NCOILS    16
#define NBATCH    2
#define TBL_LEN   6145        // 6*1024+1
#define TBL_CTR   3072
#define PLANE     (GX*GY)
#define NPTS      (NBATCH*KLEN)
#define NBINS     2048        // NBATCH * 32*32 tiles
#define NBLK      256         // sort blocks
#define PPB       2048        // points per sort block (NPTS/NBLK)

#define TROWS     21          // 16 + 5 halo
#define TQ        5           // float4 slots per record in LDS (4 used + 1 pad)

typedef _Float16 half2_t __attribute__((ext_vector_type(2)));
struct alignas(16) H8 { half2_t h[4]; };   // 4 coils' (re,im) fp16 = 16 B

// ---------------------------------------------------------------------------
// ws layout (bytes). blockHist aliases osort (dead before interp writes
// osort). btot lives in the unaliased gap: interp reads it at block start
// while other blocks may already be writing osort.
// ---------------------------------------------------------------------------
#define WS_XT       0                         // 33554432  fp16 grid records
#define WS_OSORT    33554432                  // 33554432  fp16 sorted outputs
#define WS_BHIST    33554432                  //  2097152  u32 [NBINS][NBLK] (alias osort)
#define WS_BTOT     67108864                  //     8192  u32 [NBINS]  NOT aliased
#define WS_INV      69206016                  //  2097152  u32 pos per point id
#define WS_SOM      71303168                  //  4194304  float2 om per pos
#define WS_TOTAL    75497472

__device__ inline int point_bin(float om0, float om1)
{
    const float TWO_PI = 6.2831853071795864769f;
    const float tm0 = (om0 * 512.0f) / TWO_PI;
    const float tm1 = (om1 * 512.0f) / TWO_PI;
    const int cx = ((int)floorf(tm0)) & 511;
    const int cy = ((int)floorf(tm1)) & 511;
    return ((cx >> 4) << 5) | (cy >> 4);      // [0, 1024)
}

// quad broadcast: every lane receives lane (quadbase+O)'s value. VALU op,
// stays off the LDS pipe. Only called from fully-active quads.
template<int O>
__device__ inline half2_t qbc(half2_t v)
{
    int i;
    __builtin_memcpy(&i, &v, 4);
    i = __builtin_amdgcn_mov_dpp(i, (O | (O << 2) | (O << 4) | (O << 6)),
                                 0xf, 0xf, true);
    half2_t r;
    __builtin_memcpy(&r, &i, 4);
    return r;
}

// ---------------------------------------------------------------------------
// Transpose+downconvert via LDS. Block handles 256 consecutive cells.
// ---------------------------------------------------------------------------
__global__ __launch_bounds__(256) void transpose_fp16(
    const float* __restrict__ x, float4* __restrict__ xt)
{
    __shared__ float s[32][260];   // [plane][cell], pad 260 (16B-aligned rows)
    const int blk   = blockIdx.x;            // [0, NBATCH*PLANE/256)
    const int base  = blk * 256;
    const int b     = base >> 18;
    const int cell0 = base & (PLANE - 1);
    const int t     = threadIdx.x;

    const float* xb = x + (size_t)b * 32 * PLANE + cell0;
#pragma unroll
    for (int i = 0; i < 8; ++i) {
        const int fidx = i * 256 + t;        // [0, 2048)
        const int pl = fidx >> 6;            // wave-uniform plane
        const int j  = fidx & 63;
        const float4 v = *(const float4*)(xb + (size_t)pl * PLANE + j * 4);
        *(float4*)&s[pl][j * 4] = v;
    }
    __syncthreads();
#pragma unroll
    for (int i = 0; i < 4; ++i) {
        const int chunk = i * 256 + t;       // [0, 1024)
        const int cell = chunk >> 2, q = chunk & 3;
        H8 rec;
#pragma unroll
        for (int cc = 0; cc < 4; ++cc) {
            const int c = q * 4 + cc;
            rec.h[cc] = half2_t{(_Float16)s[2 * c][cell],
                                (_Float16)s[2 * c + 1][cell]};
        }
        xt[((size_t)b * PLANE + cell0 + cell) * 4 + q] = *(const float4*)&rec;
    }
}

// ---------------------------------------------------------------------------
// Sort pass 1: per-block LDS histogram -> blockHist[bin][blk] (bin-major).
// ---------------------------------------------------------------------------
__global__ __launch_bounds__(256) void hist2d(
    const float* __restrict__ om, unsigned* __restrict__ blockHist)
{
    __shared__ unsigned h[NBINS];
    const int t = threadIdx.x, blk = blockIdx.x;
#pragma unroll
    for (int i = 0; i < NBINS / 256; ++i) h[t + i * 256] = 0u;
    __syncthreads();
#pragma unroll
    for (int i = 0; i < PPB / 256; ++i) {
        const int id = blk * PPB + i * 256 + t;
        const int b = id >> 18, m = id & (KLEN - 1);
        const float om0 = om[(size_t)(b * 2 + 0) * KLEN + m];
        const float om1 = om[(size_t)(b * 2 + 1) * KLEN + m];
        const int g = (b << 10) | point_bin(om0, om1);
        atomicAdd(&h[g], 1u);
    }
    __syncthreads();
#pragma unroll
    for (int i = 0; i < NBINS / 256; ++i) {
        const int bin = t + i * 256;
        blockHist[(size_t)bin * NBLK + blk] = h[bin];   // strided once
    }
}

// ---------------------------------------------------------------------------
// Sort pass 2: per-bin exclusive scan over NBLK block counts + per-bin total.
// ---------------------------------------------------------------------------
__global__ __launch_bounds__(256) void scan_bins(
    unsigned* __restrict__ blockHist, unsigned* __restrict__ binTotal)
{
    __shared__ unsigned partial[256];
    const int bin = blockIdx.x;
    const int t = threadIdx.x;
    const unsigned v = blockHist[(size_t)bin * NBLK + t];   // coalesced 1 KB
    partial[t] = v;
    __syncthreads();
    for (int d = 1; d < 256; d <<= 1) {
        unsigned x = (t >= d) ? partial[t - d] : 0u;
        __syncthreads();
        partial[t] += x;
        __syncthreads();
    }
    blockHist[(size_t)bin * NBLK + t] = partial[t] - v;     // exclusive
    if (t == 255) binTotal[bin] = partial[255];
}

// ---------------------------------------------------------------------------
// Sort pass 3 (was 4): final positions. Per-block LDS scan of btot replaces
// the separate scan_kernel dispatch. LDS atomics give local rank within
// (block, bin); position = binBase + blockHist + rank.
// ---------------------------------------------------------------------------
__global__ __launch_bounds__(256) void scatter2(
    const float*    __restrict__ om,
    const unsigned* __restrict__ blockHist,
    const unsigned* __restrict__ btot,
    unsigned* __restrict__ inv,
    float2* __restrict__ som)
{
    __shared__ unsigned h[NBINS];
    __shared__ unsigned bbs[NBINS];
    __shared__ unsigned part[256];
    const int t = threadIdx.x, blk = blockIdx.x;

    // exclusive scan of btot -> bbs (redundant per block; btot is L2-hot)
    unsigned v[8];
    unsigned s = 0;
#pragma unroll
    for (int i = 0; i < 8; ++i) { v[i] = btot[t * 8 + i]; s += v[i]; }
    part[t] = s;
#pragma unroll
    for (int i = 0; i < NBINS / 256; ++i) h[t + i * 256] = 0u;
    __syncthreads();
    for (int d = 1; d < 256; d <<= 1) {
        unsigned x = (t >= d) ? part[t - d] : 0u;
        __syncthreads();
        part[t] += x;
        __syncthreads();
    }
    unsigned base = (t > 0) ? part[t - 1] : 0u;
#pragma unroll
    for (int i = 0; i < 8; ++i) { bbs[t * 8 + i] = base; base += v[i]; }
    __syncthreads();

#pragma unroll
    for (int i = 0; i < PPB / 256; ++i) {
        const int id = blk * PPB + i * 256 + t;
        const int b = id >> 18, m = id & (KLEN - 1);
        const float om0 = om[(size_t)(b * 2 + 0) * KLEN + m];
        const float om1 = om[(size_t)(b * 2 + 1) * KLEN + m];
        const int g = (b << 10) | point_bin(om0, om1);
        const unsigned r = atomicAdd(&h[g], 1u);
        const unsigned pos = bbs[g] + blockHist[(size_t)g * NBLK + blk] + r;
        inv[id]  = pos;
        som[pos] = make_float2(om0, om1);
    }
}

// ---------------------------------------------------------------------------
// Main interp: ONE BLOCK PER BIN. Stage the bin's 21x21-record halo tile
// into LDS (stride TQ=5 float4 per record), then all gathers are
// ds_read_b128. 4 lanes per point; coefficient pairs computed once per quad
// and shared via DPP quad broadcast. Bin range from in-block scan of btot.
// ---------------------------------------------------------------------------
__global__ __launch_bounds__(256) void interp_bins(
    const float2*   __restrict__ som,
    const float*    __restrict__ t0,
    const float*    __restrict__ t1,
    const float4*   __restrict__ xt,
    const unsigned* __restrict__ btot,
    float4*         __restrict__ osort)
{
    __shared__ float4 tile[TROWS * TROWS * TQ];   // 2205 f4 = 35280 B
    const int bin = blockIdx.x;
    const int t   = threadIdx.x;
    const int b   = bin >> 10;
    const int cx0 = ((bin >> 5) & 31) << 4;
    const int cy0 = (bin & 31) << 4;

    // ---- bin range via in-block exclusive scan of btot (aliases tile) ---
    unsigned p0, p1e;
    {
        unsigned* sb = (unsigned*)tile;           // [0..2047] scan, [2048..] partial
        unsigned v[8];
        unsigned s = 0;
#pragma unroll
        for (int i = 0; i < 8; ++i) { v[i] = btot[t * 8 + i]; s += v[i]; }
        sb[NBINS + t] = s;
        __syncthreads();
        for (int d = 1; d < 256; d <<= 1) {
            unsigned x = (t >= d) ? sb[NBINS + t - d] : 0u;
            __syncthreads();
            sb[NBINS + t] += x;
            __syncthreads();
        }
        unsigned base = (t > 0) ? sb[NBINS + t - 1] : 0u;
#pragma unroll
        for (int i = 0; i < 8; ++i) { sb[t * 8 + i] = base; base += v[i]; }
        __syncthreads();
        p0  = sb[bin];
        p1e = (bin == NBINS - 1) ? (unsigned)NPTS : sb[bin + 1];
        __syncthreads();   // done with sb before tile overwrite
    }
    const int cnt = (int)(p1e - p0);

    // ---- stage halo tile: 441 records x 4 chunks, coalesced rows --------
    const float4* rec = xt + ((size_t)b << 20);   // b * PLANE * 4 chunks
    for (int f = t; f < TROWS * TROWS * 4; f += 256) {
        const int r = f >> 2, q = f & 3;
        const int row = r / TROWS;                // const-div -> magic mul
        const int col = r - row * TROWS;
        const int gr = (cx0 - 2 + row) & 511;
        const int gc = (cy0 - 2 + col) & 511;
        tile[r * TQ + q] = rec[(((size_t)((gr << 9) | gc)) << 2) + q];
    }
    __syncthreads();

    const int lane = t & 3;
    for (int base = 0; base < cnt; base += 64) {
        const int idx = base + (t >> 2);
        if (idx >= cnt) continue;                 // whole quad skips together
        const int pos = (int)p0 + idx;

        const float2 o = som[pos];
        const float om0 = o.x, om1 = o.y;

        const float TWO_PI = 6.2831853071795864769f;
        const float tm0 = (om0 * 512.0f) / TWO_PI;
        const float tm1 = (om1 * 512.0f) / TWO_PI;

        const float koff0 = 1.0f + floorf(tm0 - 3.0f);
        const float koff1 = 1.0f + floorf(tm1 - 3.0f);
        const int   k0    = (int)koff0;
        const int   k1    = (int)koff1;

        // c0: all 6, every lane (outer factor). c1: only this lane's j1s.
        float c0r[6], c0i[6];
        int   loff[6];
#pragma unroll
        for (int j = 0; j < 6; ++j) {
            const float g0 = koff0 + (float)j;
            const int   d0 = (int)rintf((tm0 - g0) * 1024.0f) + TBL_CTR;
            c0r[j] = t0[d0];
            c0i[j] = t0[TBL_LEN + d0];
            loff[j] = ((k1 + j - cy0 + 2) & 511) * TQ;   // in [0, 20]*TQ
        }
        const int j1a = lane;                       // pair A owner: lane j1
        const int j1b = (lane < 2) ? lane + 4 : lane;   // pair B (lanes 0,1)
        const int d1a = (int)rintf((tm1 - (koff1 + (float)j1a)) * 1024.0f) + TBL_CTR;
        const int d1b = (int)rintf((tm1 - (koff1 + (float)j1b)) * 1024.0f) + TBL_CTR;
        const float c1ra = t1[d1a], c1ia = t1[TBL_LEN + d1a];
        const float c1rb = t1[d1b], c1ib = t1[TBL_LEN + d1b];

        float acr[4] = {0.f, 0.f, 0.f, 0.f};
        float aci[4] = {0.f, 0.f, 0.f, 0.f};

#define KB_DO_J1(JJ, OWNER, PP1, PP2)                                         \
        do {                                                                  \
            const half2_t p1 = qbc<OWNER>(PP1);                               \
            const half2_t p2 = qbc<OWNER>(PP2);                               \
            const float4 raw = rowp[loff[JJ]];                                \
            const H8 v = *(const H8*)&raw;                                    \
            _Pragma("unroll")                                                 \
            for (int cc = 0; cc < 4; ++cc) {                                  \
                acr[cc] = __builtin_amdgcn_fdot2(v.h[cc], p1, acr[cc], false);\
                aci[cc] = __builtin_amdgcn_fdot2(v.h[cc], p2, aci[cc], false);\
            }                                                                 \
        } while (0)

#pragma unroll
        for (int j0 = 0; j0 < 6; ++j0) {
            const int rIdx = (k0 + j0 - cx0 + 2) & 511;  // in [0, 20]
            const float4* rowp = &tile[rIdx * (TROWS * TQ) + lane];
            const float ar = c0r[j0], ai = c0i[j0];
            // this lane's pairs (same f32 math every lane ran before R11)
            const float crA = ar * c1ra - ai * c1ia;
            const float ciA = ar * c1ia + ai * c1ra;
            const float crB = ar * c1rb - ai * c1ib;
            const float ciB = ar * c1ib + ai * c1rb;
            const half2_t pA1 = {(_Float16)crA, (_Float16)(-ciA)};
            const half2_t pA2 = {(_Float16)ciA, (_Float16)crA};
            const half2_t pB1 = {(_Float16)crB, (_Float16)(-ciB)};
            const half2_t pB2 = {(_Float16)ciB, (_Float16)crB};

            KB_DO_J1(0, 0, pA1, pA2);
            KB_DO_J1(1, 1, pA1, pA2);
            KB_DO_J1(2, 2, pA1, pA2);
            KB_DO_J1(3, 3, pA1, pA2);
            KB_DO_J1(4, 0, pB1, pB2);
            KB_DO_J1(5, 1, pB1, pB2);
        }
#undef KB_DO_J1

        // phase twist: exp(i * (om0+om1)*128); |ph| <= 128 rev -> native ok
        const float ph = om0 * 128.0f + om1 * 128.0f;
        const float s = __sinf(ph), c = __cosf(ph);

        H8 outrec;
#pragma unroll
        for (int cc = 0; cc < 4; ++cc) {
            const float yr = acr[cc] * c - aci[cc] * s;
            const float yi = acr[cc] * s + aci[cc] * c;
            outrec.h[cc] = half2_t{(_Float16)yr, (_Float16)yi};
        }
        osort[(size_t)pos * 4 + lane] = *(const float4*)&outrec;   // coalesced
    }
}

// ---------------------------------------------------------------------------
// Unsort: thread per point id; gather 64 B record from osort, store coalesced
// into final (b,c,ri,m) layout.
// ---------------------------------------------------------------------------
__global__ __launch_bounds__(256) void unsort_kernel(
    const unsigned* __restrict__ inv,
    const float4*   __restrict__ osort,
    float*          __restrict__ out)
{
    const int id = blockIdx.x * blockDim.x + threadIdx.x;   // [0, NPTS)
    const int b = id >> 18, m = id & (KLEN - 1);
    const unsigned pos = inv[id];
    const float4* rp = osort + (size_t)pos * 4;

    float4 raw[4];
#pragma unroll
    for (int q = 0; q < 4; ++q) raw[q] = rp[q];

    float* ob = out + (size_t)b * NCOILS * 2 * KLEN + m;
#pragma unroll
    for (int q = 0; q < 4; ++q) {
        const H8 v = *(const H8*)&raw[q];
#pragma unroll
        for (int cc = 0; cc < 4; ++cc) {
            const int coil = q * 4 + cc;
            ob[(size_t)(2 * coil)     * KLEN] = (float)v.h[cc].x;
            ob[(size_t)(2 * coil + 1) * KLEN] = (float)v.h[cc].y;
        }
    }
}

// ---------------------------------------------------------------------------
// Middle path (ws >= xt only): direct-order interp (4 lanes/point).
// ---------------------------------------------------------------------------
__global__ __launch_bounds__(256) void interp_direct(
    const float*  __restrict__ om,
    const float*  __restrict__ t0,
    const float*  __restrict__ t1,
    const float4* __restrict__ xt,
    float*        __restrict__ out)
{
    const int tid  = blockIdx.x * blockDim.x + threadIdx.x;
    const int lane = tid & 3;
    const int p    = tid >> 2;
    const int b    = p >> 18;
    const int m    = p & (KLEN - 1);

    const float om0 = om[(size_t)(b * 2 + 0) * KLEN + m];
    const float om1 = om[(size_t)(b * 2 + 1) * KLEN + m];

    const float TWO_PI = 6.2831853071795864769f;
    const float tm0 = (om0 * 512.0f) / TWO_PI;
    const float tm1 = (om1 * 512.0f) / TWO_PI;
    const float koff0 = 1.0f + floorf(tm0 - 3.0f);
    const float koff1 = 1.0f + floorf(tm1 - 3.0f);
    const int k0 = (int)koff0, k1 = (int)koff1;

    float c0r[6], c0i[6], c1r[6], c1i[6];
    int coff[6];
#pragma unroll
    for (int j = 0; j < 6; ++j) {
        const float g0 = koff0 + (float)j;
        const int d0 = (int)rintf((tm0 - g0) * 1024.0f) + TBL_CTR;
        c0r[j] = t0[d0];
        c0i[j] = t0[TBL_LEN + d0];
        const float g1 = koff1 + (float)j;
        const int d1 = (int)rintf((tm1 - g1) * 1024.0f) + TBL_CTR;
        c1r[j] = t1[d1];
        c1i[j] = t1[TBL_LEN + d1];
        coff[j] = ((k1 + j) & 511) << 2;
    }

    const float4* rec = xt + ((size_t)b << 20);
    float acr[4] = {0.f, 0.f, 0.f, 0.f};
    float aci[4] = {0.f, 0.f, 0.f, 0.f};
#pragma unroll
    for (int j0 = 0; j0 < 6; ++j0) {
        const int roff = (k0 + j0) & 511;
        const float4* rowp = rec + ((size_t)roff << 11) + lane;
        const float ar = c0r[j0], ai = c0i[j0];
#pragma unroll
        for (int j1 = 0; j1 < 6; ++j1) {
            const float br = c1r[j1], bi = c1i[j1];
            const float cr = ar * br - ai * bi;
            const float ci = ar * bi + ai * br;
            const half2_t p1 = {(_Float16)cr, (_Float16)(-ci)};
            const half2_t p2 = {(_Float16)ci, (_Float16)cr};
            const float4 raw = rowp[coff[j1]];
            const H8 v = *(const H8*)&raw;
#pragma unroll
            for (int cc = 0; cc < 4; ++cc) {
                acr[cc] = __builtin_amdgcn_fdot2(v.h[cc], p1, acr[cc], false);
                aci[cc] = __builtin_amdgcn_fdot2(v.h[cc], p2, aci[cc], false);
            }
        }
    }

    const float ph = om0 * 128.0f + om1 * 128.0f;
    const float s = sinf(ph), c = cosf(ph);
#pragma unroll
    for (int cc = 0; cc < 4; ++cc) {
        const float yr = acr[cc] * c - aci[cc] * s;
        const float yi = acr[cc] * s + aci[cc] * c;
        const int coil = lane * 4 + cc;
        const size_t ob = ((size_t)(b * NCOILS + coil) * 2) * KLEN + m;
        out[ob]        = yr;
        out[ob + KLEN] = yi;
    }
}

// ---------------------------------------------------------------------------
// Fallback (tiny ws): one thread per point, original layout.
// ---------------------------------------------------------------------------
__global__ __launch_bounds__(256) void interp_fallback(
    const float* __restrict__ om,
    const float* __restrict__ t0,
    const float* __restrict__ t1,
    const float* __restrict__ x,
    float*       __restrict__ out)
{
    const int p = blockIdx.x * blockDim.x + threadIdx.x;
    const int b = p >> 18;
    const int m = p & (KLEN - 1);

    const float om0 = om[(size_t)(b * 2 + 0) * KLEN + m];
    const float om1 = om[(size_t)(b * 2 + 1) * KLEN + m];
    const float TWO_PI = 6.2831853071795864769f;
    const float tm0 = (om0 * 512.0f) / TWO_PI;
    const float tm1 = (om1 * 512.0f) / TWO_PI;
    const float koff0 = 1.0f + floorf(tm0 - 3.0f);
    const float koff1 = 1.0f + floorf(tm1 - 3.0f);
    const int k0 = (int)koff0, k1 = (int)koff1;

    float c0r[6], c0i[6], c1r[6], c1i[6];
    int roff[6], coff[6];
#pragma unroll
    for (int j = 0; j < 6; ++j) {
        const float g0 = koff0 + (float)j;
        const int d0 = (int)rintf((tm0 - g0) * 1024.0f) + TBL_CTR;
        c0r[j] = t0[d0];
        c0i[j] = t0[TBL_LEN + d0];
        const float g1 = koff1 + (float)j;
        const int d1 = (int)rintf((tm1 - g1) * 1024.0f) + TBL_CTR;
        c1r[j] = t1[d1];
        c1i[j] = t1[TBL_LEN + d1];
        roff[j] = (k0 + j) & 511;
        coff[j] = (k1 + j) & 511;
    }

    float accr[NCOILS], acci[NCOILS];
#pragma unroll
    for (int c = 0; c < NCOILS; ++c) { accr[c] = 0.f; acci[c] = 0.f; }

    const float* xb = x + (size_t)b * NCOILS * 2 * PLANE;
#pragma unroll
    for (int j0 = 0; j0 < 6; ++j0) {
        const float ar = c0r[j0], ai = c0i[j0];
        const int rb = roff[j0] * GY;
#pragma unroll
        for (int j1 = 0; j1 < 6; ++j1) {
            const float br = c1r[j1], bi = c1i[j1];
            const float cr = ar * br - ai * bi;
            const float ci = ar * bi + ai * br;
            const int ai_idx = rb + coff[j1];
#pragma unroll
            for (int c = 0; c < NCOILS; ++c) {
                const float dr = xb[(size_t)c * (2 * PLANE) + ai_idx];
                const float di = xb[(size_t)c * (2 * PLANE) + PLANE + ai_idx];
                accr[c] += cr * dr - ci * di;
                acci[c] += cr * di + ci * dr;
            }
        }
    }

    const float ph = om0 * 128.0f + om1 * 128.0f;
    const float s = sinf(ph), c = cosf(ph);
#pragma unroll
    for (int cc = 0; cc < NCOILS; ++cc) {
        const float yr = accr[cc] * c - acci[cc] * s;
        const float yi = accr[cc] * s + acci[cc] * c;
        size_t ob = ((size_t)(b * NCOILS + cc) * 2) * KLEN + m;
        out[ob]        = yr;
        out[ob + KLEN] = yi;
    }
}

extern "C" void kernel_launch(void* const* d_in, const int* in_sizes, int n_in,
                              void* d_out, int out_size, void* d_ws, size_t ws_size,
                              hipStream_t stream)
{
    const float* x  = (const float*)d_in[0];
    const float* om = (const float*)d_in[1];
    const float* t0 = (const float*)d_in[2];
    const float* t1 = (const float*)d_in[3];
    float* out = (float*)d_out;

    char* ws = (char*)d_ws;
    const size_t xt_bytes = (size_t)NBATCH * PLANE * NCOILS * 2 * sizeof(__half);

    if (ws_size >= (size_t)WS_TOTAL) {
        float4*   xt     = (float4*)(ws + WS_XT);
        float4*   osort  = (float4*)(ws + WS_OSORT);
        unsigned* bhist  = (unsigned*)(ws + WS_BHIST);
        unsigned* btot   = (unsigned*)(ws + WS_BTOT);
        unsigned* inv    = (unsigned*)(ws + WS_INV);
        float2*   som    = (float2*)(ws + WS_SOM);

        transpose_fp16<<<NBATCH * PLANE / 256, 256, 0, stream>>>(x, xt);
        hist2d<<<NBLK, 256, 0, stream>>>(om, bhist);
        scan_bins<<<NBINS, 256, 0, stream>>>(bhist, btot);
        scatter2<<<NBLK, 256, 0, stream>>>(om, bhist, btot, inv, som);
        interp_bins<<<NBINS, 256, 0, stream>>>(som, t0, t1, xt, btot, osort);
        unsort_kernel<<<NPTS / 256, 256, 0, stream>>>(inv, osort, out);
    } else if (ws_size >= xt_bytes) {
        float4* xt = (float4*)ws;
        transpose_fp16<<<NBATCH * PLANE / 256, 256, 0, stream>>>(x, xt);
        interp_direct<<<NPTS * 4 / 256, 256, 0, stream>>>(om, t0, t1, xt, out);
    } else {
        interp_fallback<<<NPTS / 256, 256, 0, stream>>>(om, t0, t1, x, out);
    }
}